// Round 1
// baseline (891.314 us; speedup 1.0000x reference)
//
#include <hip/hip_runtime.h>
#include <hip/hip_fp16.h>

// 3-layer GCN (fp32 compute): bucketed CSR build + (GEMM -> gather-aggregate) x3
// + final linear.
// Round 7: k_gemm1 moved to the matrix pipe. fp32 has no MFMA on CDNA4, so we
// use a 3-term split-f16 scheme (X=Xh+Xl, W=Wh+Wl; XhWh+XhWl+XlWh in fp32
// accumulators) with v_mfma_f32_16x16x32_f16 -> ~fp32 precision (~2^-21 rel),
// absmax expected unchanged. W is pre-split/transposed once (k_prepw) into
// k-major f16 so B-fragments are 16B-contiguous global loads (L2-resident).
// X tile staged fp32->hi/lo f16 in LDS [128][40] (2-way banks = free), with
// register prefetch of the next K-tile issued before the MFMA phase.

#define N_NODES 200000
#define N_EDGES 3200000
#define NBUCK 782            // ceil(200000/256)

static_assert(N_NODES % 64 == 0, "tiling");
static_assert((NBUCK - 1) * 256 < N_NODES && NBUCK * 256 >= N_NODES, "buckets");

typedef unsigned int u32;
typedef _Float16 f16;
typedef __attribute__((ext_vector_type(8))) _Float16 f16x8;
typedef __attribute__((ext_vector_type(4))) float f32x4;

// ---------------- bucket histogram ----------------

__global__ __launch_bounds__(256) void k_bhist(const int* __restrict__ dst,
                                               int* __restrict__ bcnt) {
    __shared__ int lh[NBUCK];
    int t = threadIdx.x;
    for (int b = t; b < NBUCK; b += 256) lh[b] = 0;
    __syncthreads();
    long e0 = (long)blockIdx.x * 8192;
    for (int k = 0; k < 32; ++k) {
        long e = e0 + k * 256 + t;
        if (e < N_EDGES) atomicAdd(&lh[dst[e] >> 8], 1);
    }
    __syncthreads();
    for (int b = t; b < NBUCK; b += 256)
        if (lh[b]) atomicAdd(&bcnt[b], lh[b]);
}

// ---------------- bucket scan (1 block) ----------------

__global__ __launch_bounds__(256) void k_bscan(const int* __restrict__ bcnt,
                                               int* __restrict__ boff,
                                               int* __restrict__ bcur,
                                               int* __restrict__ row) {
    __shared__ int sm[256];
    int t = threadIdx.x;
    int base = t * 4;
    int a0 = (base + 0 < NBUCK) ? bcnt[base + 0] : 0;
    int a1 = (base + 1 < NBUCK) ? bcnt[base + 1] : 0;
    int a2 = (base + 2 < NBUCK) ? bcnt[base + 2] : 0;
    int a3 = (base + 3 < NBUCK) ? bcnt[base + 3] : 0;
    int s = a0 + a1 + a2 + a3;
    sm[t] = s;
    __syncthreads();
    for (int o = 1; o < 256; o <<= 1) {
        int v = (t >= o) ? sm[t - o] : 0;
        __syncthreads();
        sm[t] += v;
        __syncthreads();
    }
    int excl = sm[t] - s;
    if (base + 0 < NBUCK) { boff[base + 0] = excl;               bcur[base + 0] = excl; }
    if (base + 1 < NBUCK) { boff[base + 1] = excl + a0;          bcur[base + 1] = excl + a0; }
    if (base + 2 < NBUCK) { boff[base + 2] = excl + a0 + a1;     bcur[base + 2] = excl + a0 + a1; }
    if (base + 3 < NBUCK) { boff[base + 3] = excl + a0 + a1 + a2; bcur[base + 3] = excl + a0 + a1 + a2; }
    if (t == 255) { boff[NBUCK] = N_EDGES; row[N_NODES] = N_EDGES; }
}

// ------------- chunked scatter: entries[p] = (src<<8)|dst_local -------------

__global__ __launch_bounds__(256) void k_scatter(const int* __restrict__ src,
                                                 const int* __restrict__ dst,
                                                 int* __restrict__ bcur,
                                                 u32* __restrict__ entries) {
    __shared__ int lh[NBUCK];
    __shared__ int base[NBUCK];
    __shared__ int lcur[NBUCK];
    int t = threadIdx.x;
    for (int b = t; b < NBUCK; b += 256) lh[b] = 0;
    __syncthreads();
    long e0 = (long)blockIdx.x * 8192;
    for (int k = 0; k < 32; ++k) {
        long e = e0 + k * 256 + t;
        if (e < N_EDGES) atomicAdd(&lh[dst[e] >> 8], 1);
    }
    __syncthreads();
    for (int b = t; b < NBUCK; b += 256) {
        base[b] = atomicAdd(&bcur[b], lh[b]);
        lcur[b] = 0;
    }
    __syncthreads();
    for (int k = 0; k < 32; ++k) {
        long e = e0 + k * 256 + t;
        if (e < N_EDGES) {
            int d = dst[e];
            int bkt = d >> 8;
            int p = base[bkt] + atomicAdd(&lcur[bkt], 1);
            entries[p] = ((u32)src[e] << 8) | (u32)(d & 255);
        }
    }
}

// --- per-bucket prep: deg/row/dinv + col fill, all L2-local to one block ----

__global__ __launch_bounds__(256) void k_prep(const u32* __restrict__ entries,
                                              const int* __restrict__ boff,
                                              int* __restrict__ row,
                                              float* __restrict__ dinv,
                                              int* __restrict__ col) {
    __shared__ int lh[256];
    __shared__ int sc[256];
    __shared__ int cur[256];
    const int b = blockIdx.x, t = threadIdx.x;
    const int s = boff[b], e = boff[b + 1];
    const int cnt = e - s;
    lh[t] = 0;
    __syncthreads();
    for (int i = t; i < cnt; i += 256) atomicAdd(&lh[entries[s + i] & 255], 1);
    __syncthreads();
    int my = lh[t];
    sc[t] = my;
    __syncthreads();
    for (int o = 1; o < 256; o <<= 1) {
        int v = (t >= o) ? sc[t - o] : 0;
        __syncthreads();
        sc[t] += v;
        __syncthreads();
    }
    int excl = sc[t] - my;
    int node = b * 256 + t;
    if (node < N_NODES) {
        row[node] = s + excl;
        dinv[node] = rsqrtf((float)(my + 1));  // +1 self-loop
    }
    cur[t] = s + excl;
    __syncthreads();
    for (int i = t; i < cnt; i += 256) {
        u32 en = entries[s + i];
        int p = atomicAdd(&cur[en & 255], 1);
        col[p] = (int)(en >> 8);
    }
}

// ------- W1 pre-split/transpose: Wth/Wtl[f][k] f16 hi/lo, k-major -----------

__global__ __launch_bounds__(256) void k_prepw(const float* __restrict__ W,
                                               f16* __restrict__ Wth,
                                               f16* __restrict__ Wtl) {
    int t = blockIdx.x * 256 + threadIdx.x;  // 0..32767
    int k = t >> 7;                          // 0..255 (tail rows 256/257 stay fp32)
    int f = t & 127;
    float w = W[k * 128 + f];
    f16 hi = (f16)w;
    f16 lo = (f16)(w - (float)hi);
    Wth[f * 256 + k] = hi;
    Wtl[f * 256 + k] = lo;
}

// ------- GEMM layer 1 (MFMA): [N,258]x[258,128], epilogue g = dinv*h -> fp16
// Block: 128 nodes x 128 feats, 4 waves, wave owns 32 nodes x 128 feats.
// D = mfma(Wfrag, Xfrag): lane owns node=l&15, feats 4*(l>>4)+r (consecutive)
// -> packed 8B half stores. 3-term split-f16 => fp32-equivalent precision.

__global__ __launch_bounds__(256) void k_gemm1(const float* __restrict__ X,
                                               const float* __restrict__ hist,
                                               const float* __restrict__ subg,
                                               const float* __restrict__ W,
                                               const f16* __restrict__ Wth,
                                               const f16* __restrict__ Wtl,
                                               const float* __restrict__ dinv,
                                               __half2* __restrict__ g1) {
    __shared__ f16 Ah[128][40];   // [node][k], +8 pad -> 2-way banks (free)
    __shared__ f16 Al[128][40];
    const int t = threadIdx.x;
    const int nb = blockIdx.x * 128;
    const int wv = t >> 6;         // wave 0..3
    const int l = t & 63;
    const int l15 = l & 15;
    const int lk = l >> 4;         // k-chunk 0..3 (8 k each)

    // staging role: thread loads 16 floats of one row-half
    const int srow = t >> 1;            // 0..127
    const int skh = (t & 1) * 16;       // k-offset 0 / 16
    int xrow = nb + srow;
    if (xrow >= N_NODES) xrow = N_NODES - 1;  // clamp (junk, stores guarded)
    const float* xbase = X + (size_t)xrow * 256 + skh;

    f32x4 acc[8][2];
#pragma unroll
    for (int fb = 0; fb < 8; ++fb)
#pragma unroll
        for (int nf = 0; nf < 2; ++nf) acc[fb][nf] = (f32x4){0.f, 0.f, 0.f, 0.f};

    // prefetch tile 0
    float4 pre0 = *(const float4*)(xbase + 0);
    float4 pre1 = *(const float4*)(xbase + 4);
    float4 pre2 = *(const float4*)(xbase + 8);
    float4 pre3 = *(const float4*)(xbase + 12);

    const int nloc0 = wv * 32 + l15;    // node-local for nf=0; +16 for nf=1

    for (int kc = 0; kc < 256; kc += 32) {
        if (kc) __syncthreads();  // all reads of previous tile done

        // convert fp32 -> hi/lo f16, write to LDS
        {
            float xs[16] = {pre0.x, pre0.y, pre0.z, pre0.w,
                            pre1.x, pre1.y, pre1.z, pre1.w,
                            pre2.x, pre2.y, pre2.z, pre2.w,
                            pre3.x, pre3.y, pre3.z, pre3.w};
            union { f16 h[16]; f16x8 v[2]; } H, L;
#pragma unroll
            for (int i = 0; i < 16; ++i) {
                f16 h = (f16)xs[i];
                H.h[i] = h;
                L.h[i] = (f16)(xs[i] - (float)h);
            }
            *(f16x8*)&Ah[srow][skh + 0] = H.v[0];
            *(f16x8*)&Ah[srow][skh + 8] = H.v[1];
            *(f16x8*)&Al[srow][skh + 0] = L.v[0];
            *(f16x8*)&Al[srow][skh + 8] = L.v[1];
        }

        // issue next-tile loads before the compute phase (latency hides under MFMA)
        if (kc + 32 < 256) {
            const float* xp = xbase + kc + 32;
            pre0 = *(const float4*)(xp + 0);
            pre1 = *(const float4*)(xp + 4);
            pre2 = *(const float4*)(xp + 8);
            pre3 = *(const float4*)(xp + 12);
        }
        __syncthreads();  // tile visible

        // X fragments (B-operand): lane holds X[node][kc+8*lk .. +7]
        f16x8 xh0 = *(const f16x8*)&Ah[nloc0][lk * 8];
        f16x8 xl0 = *(const f16x8*)&Al[nloc0][lk * 8];
        f16x8 xh1 = *(const f16x8*)&Ah[nloc0 + 16][lk * 8];
        f16x8 xl1 = *(const f16x8*)&Al[nloc0 + 16][lk * 8];

        // W fragments (A-operand) straight from global (L2-resident, 16B/lane)
        const f16* wbh = Wth + (size_t)l15 * 256 + kc + lk * 8;
        const f16* wbl = Wtl + (size_t)l15 * 256 + kc + lk * 8;
#pragma unroll
        for (int fb = 0; fb < 8; ++fb) {
            f16x8 wh = *(const f16x8*)(wbh + (size_t)fb * 16 * 256);
            f16x8 wl = *(const f16x8*)(wbl + (size_t)fb * 16 * 256);
            acc[fb][0] = __builtin_amdgcn_mfma_f32_16x16x32_f16(wh, xh0, acc[fb][0], 0, 0, 0);
            acc[fb][0] = __builtin_amdgcn_mfma_f32_16x16x32_f16(wh, xl0, acc[fb][0], 0, 0, 0);
            acc[fb][0] = __builtin_amdgcn_mfma_f32_16x16x32_f16(wl, xh0, acc[fb][0], 0, 0, 0);
            acc[fb][1] = __builtin_amdgcn_mfma_f32_16x16x32_f16(wh, xh1, acc[fb][1], 0, 0, 0);
            acc[fb][1] = __builtin_amdgcn_mfma_f32_16x16x32_f16(wh, xl1, acc[fb][1], 0, 0, 0);
            acc[fb][1] = __builtin_amdgcn_mfma_f32_16x16x32_f16(wl, xh1, acc[fb][1], 0, 0, 0);
        }
    }

    // epilogue: K tail rows 256 (hist), 257 (subg) in exact fp32; scale dinv.
#pragma unroll
    for (int nf = 0; nf < 2; ++nf) {
        int node = nb + wv * 32 + nf * 16 + l15;
        bool ok = node < N_NODES;
        int nc = ok ? node : (N_NODES - 1);
        float hh = hist[nc];
        float ss = subg[nc];
        float dv = dinv[nc];
        char* orow = (char*)g1 + (size_t)node * 256;
#pragma unroll
        for (int fb = 0; fb < 8; ++fb) {
            int f0 = fb * 16 + lk * 4;  // 4 consecutive feats per lane
            float4 w6 = *(const float4*)(W + 256 * 128 + f0);
            float4 w7 = *(const float4*)(W + 257 * 128 + f0);
            union { f16 h[4]; float2 v; } o;
            o.h[0] = (f16)((acc[fb][nf][0] + hh * w6.x + ss * w7.x) * dv);
            o.h[1] = (f16)((acc[fb][nf][1] + hh * w6.y + ss * w7.y) * dv);
            o.h[2] = (f16)((acc[fb][nf][2] + hh * w6.z + ss * w7.z) * dv);
            o.h[3] = (f16)((acc[fb][nf][3] + hh * w6.w + ss * w7.w) * dv);
            if (ok) *(float2*)(orow + fb * 32 + lk * 8) = o.v;
        }
    }
}

// ------- GEMM layer 2: [N,128]x[128,64] fp32, epilogue g = dinv*h -> fp16 ----

__global__ __launch_bounds__(256) void k_gemm2(const float* __restrict__ Xin,
                                               const float* __restrict__ W,
                                               const float* __restrict__ dinv,
                                               __half2* __restrict__ g2) {
    __shared__ float Xs[64][33];
    __shared__ float Ws[32][68];
    const int t = threadIdx.x;
    const int nb = blockIdx.x * 64;
    const int fi = t & 15;
    const int ni = t >> 4;
    const int lxn = t >> 2;
    const int lxk = (t & 3) * 8;
    const int lwk = t >> 3;
    const int lwf = (t & 7) * 8;

    float acc[4][4];
#pragma unroll
    for (int n = 0; n < 4; ++n)
#pragma unroll
        for (int f = 0; f < 4; ++f) acc[n][f] = 0.f;

    for (int kc = 0; kc < 128; kc += 32) {
        const float* xp = Xin + (size_t)(nb + lxn) * 128 + kc + lxk;
        float4 xa = *(const float4*)xp;
        float4 xb = *(const float4*)(xp + 4);
        Xs[lxn][lxk + 0] = xa.x;
        Xs[lxn][lxk + 1] = xa.y;
        Xs[lxn][lxk + 2] = xa.z;
        Xs[lxn][lxk + 3] = xa.w;
        Xs[lxn][lxk + 4] = xb.x;
        Xs[lxn][lxk + 5] = xb.y;
        Xs[lxn][lxk + 6] = xb.z;
        Xs[lxn][lxk + 7] = xb.w;

        const float* wp = W + (size_t)(kc + lwk) * 64 + lwf;
        float4* wsp = (float4*)&Ws[lwk][lwf];
        wsp[0] = *(const float4*)(wp + 0);
        wsp[1] = *(const float4*)(wp + 4);
        __syncthreads();

#pragma unroll
        for (int kk = 0; kk < 32; ++kk) {
            float4 wv = *(const float4*)&Ws[kk][fi * 4];
#pragma unroll
            for (int n = 0; n < 4; ++n) {
                float xv = Xs[ni * 4 + n][kk];
                acc[n][0] += xv * wv.x;
                acc[n][1] += xv * wv.y;
                acc[n][2] += xv * wv.z;
                acc[n][3] += xv * wv.w;
            }
        }
        __syncthreads();
    }

#pragma unroll
    for (int n = 0; n < 4; ++n) {
        float dv = dinv[nb + ni * 4 + n];
        float2 pk;
        __half2* ph = (__half2*)&pk;
#pragma unroll
        for (int k = 0; k < 2; ++k) {
            __half2 h;
            h.x = __float2half_rn(acc[n][2 * k + 0] * dv);
            h.y = __float2half_rn(acc[n][2 * k + 1] * dv);
            ph[k] = h;
        }
        *(float2*)(g2 + (size_t)(nb + ni * 4 + n) * 32 + fi * 2) = pk;
    }
}

// ------- GEMM layer 3: [N,64]x[64,8], epilogue g = dinv*h (fp32) -------------

__global__ __launch_bounds__(256) void k_gemm3(const float* __restrict__ Xin,
                                               const float* __restrict__ W,
                                               const float* __restrict__ dinv,
                                               float* __restrict__ g3) {
    __shared__ float Ws[512];
    int t = threadIdx.x;
    Ws[t] = W[t];
    Ws[t + 256] = W[t + 256];
    __syncthreads();
    int i = blockIdx.x * 256 + t;
    if (i >= N_NODES) return;
    const float4* xp = (const float4*)(Xin + (size_t)i * 64);
    float acc[8];
#pragma unroll
    for (int f = 0; f < 8; ++f) acc[f] = 0.f;
#pragma unroll
    for (int k4 = 0; k4 < 16; ++k4) {
        float4 xv = xp[k4];
        float xs[4] = {xv.x, xv.y, xv.z, xv.w};
#pragma unroll
        for (int q = 0; q < 4; ++q) {
            int k = k4 * 4 + q;
            float4 w0 = *(const float4*)&Ws[k * 8];
            float4 w1 = *(const float4*)&Ws[k * 8 + 4];
            acc[0] += xs[q] * w0.x;
            acc[1] += xs[q] * w0.y;
            acc[2] += xs[q] * w0.z;
            acc[3] += xs[q] * w0.w;
            acc[4] += xs[q] * w1.x;
            acc[5] += xs[q] * w1.y;
            acc[6] += xs[q] * w1.z;
            acc[7] += xs[q] * w1.w;
        }
    }
    float dv = dinv[i];
    float* op = g3 + (size_t)i * 8;
    *(float4*)op = make_float4(acc[0] * dv, acc[1] * dv, acc[2] * dv, acc[3] * dv);
    *(float4*)(op + 4) = make_float4(acc[4] * dv, acc[5] * dv, acc[6] * dv, acc[7] * dv);
}

// ------- aggregation (fp16 payload): out[i] = relu(dinv_i*(sum_j g_j + g_i)+b)

template <int F, int TPN>
__global__ __launch_bounds__(256) void k_aggh(const __half2* __restrict__ g,
                                              const int* __restrict__ row,
                                              const int* __restrict__ col,
                                              const float* __restrict__ dinv,
                                              const float* __restrict__ bias,
                                              float* __restrict__ out) {
    constexpr int H2 = F / 2;
    static_assert(TPN == H2, "one half2 per lane");
    constexpr int NPB = 256 / TPN;
    const int t = threadIdx.x;
    const int node = blockIdx.x * NPB + t / TPN;
    const int lane = t % TPN;

    float ax = 0.f, ay = 0.f;
    const int s = row[node];
    const int e = row[node + 1];
    int idx = s;
    for (; idx + 8 <= e; idx += 8) {
        int j[8];
#pragma unroll
        for (int u = 0; u < 8; ++u) j[u] = col[idx + u];
        __half2 h[8];
#pragma unroll
        for (int u = 0; u < 8; ++u) h[u] = g[(size_t)j[u] * H2 + lane];
#pragma unroll
        for (int u = 0; u < 8; ++u) {
            float2 f = __half22float2(h[u]);
            ax += f.x;
            ay += f.y;
        }
    }
    for (; idx < e; ++idx) {
        float2 f = __half22float2(g[(size_t)col[idx] * H2 + lane]);
        ax += f.x;
        ay += f.y;
    }
    float2 fs = __half22float2(g[(size_t)node * H2 + lane]);  // self-loop
    const float di = dinv[node];
    float2 b = *(const float2*)(bias + lane * 2);
    float2 o;
    o.x = fmaxf(di * (ax + fs.x) + b.x, 0.f);
    o.y = fmaxf(di * (ay + fs.y) + b.y, 0.f);
    *(float2*)(out + (size_t)node * F + lane * 2) = o;
}

// ------- aggregation layer 3 (fp32, F=8, pre-scaled payload) -----------------

__global__ __launch_bounds__(256) void k_agg8(const float* __restrict__ g,
                                              const int* __restrict__ row,
                                              const int* __restrict__ col,
                                              const float* __restrict__ dinv,
                                              const float* __restrict__ bias,
                                              float* __restrict__ out) {
    const int t = threadIdx.x;
    const int node = blockIdx.x * 32 + t / 8;
    const int lane = t & 7;
    float acc = 0.f;
    const int s = row[node];
    const int e = row[node + 1];
    int idx = s;
    for (; idx + 8 <= e; idx += 8) {
        int j[8];
#pragma unroll
        for (int u = 0; u < 8; ++u) j[u] = col[idx + u];
        float v[8];
#pragma unroll
        for (int u = 0; u < 8; ++u) v[u] = g[(size_t)j[u] * 8 + lane];
#pragma unroll
        for (int u = 0; u < 8; ++u) acc += v[u];
    }
    for (; idx < e; ++idx) acc += g[(size_t)col[idx] * 8 + lane];
    acc += g[(size_t)node * 8 + lane];  // self-loop
    out[(size_t)node * 8 + lane] = fmaxf(dinv[node] * acc + bias[lane], 0.f);
}

// ---------------- final linear: [N,8]x[8,3] + bc -----------------------------

__global__ __launch_bounds__(256) void k_final(const float* __restrict__ h,
                                               const float* __restrict__ Wc,
                                               const float* __restrict__ bc,
                                               float* __restrict__ out) {
    int i = blockIdx.x * 256 + threadIdx.x;
    if (i >= N_NODES) return;
    const float4* xp = (const float4*)(h + (size_t)i * 8);
    float4 x0 = xp[0], x1 = xp[1];
    float xs[8] = {x0.x, x0.y, x0.z, x0.w, x1.x, x1.y, x1.z, x1.w};
    float o0 = bc[0], o1 = bc[1], o2 = bc[2];
#pragma unroll
    for (int k = 0; k < 8; ++k) {
        o0 += xs[k] * Wc[k * 3 + 0];
        o1 += xs[k] * Wc[k * 3 + 1];
        o2 += xs[k] * Wc[k * 3 + 2];
    }
    out[(size_t)i * 3 + 0] = o0;
    out[(size_t)i * 3 + 1] = o1;
    out[(size_t)i * 3 + 2] = o2;
}

// ---------------- launch -----------------------------------------------------

extern "C" void kernel_launch(void* const* d_in, const int* in_sizes, int n_in,
                              void* d_out, int out_size, void* d_ws, size_t ws_size,
                              hipStream_t stream) {
    const float* latent = (const float*)d_in[0];
    const float* hist = (const float*)d_in[1];
    const float* subg = (const float*)d_in[2];
    const int* eidx = (const int*)d_in[3];
    const float* W1 = (const float*)d_in[4];
    const float* b1 = (const float*)d_in[5];
    const float* W2 = (const float*)d_in[6];
    const float* b2 = (const float*)d_in[7];
    const float* W3 = (const float*)d_in[8];
    const float* b3 = (const float*)d_in[9];
    const float* Wc = (const float*)d_in[10];
    const float* bc = (const float*)d_in[11];
    float* outp = (float*)d_out;

    char* ws = (char*)d_ws;
    size_t off = 0;
    auto take = [&](size_t bytes) -> void* {
        void* p = ws + off;
        off += (bytes + 255) & ~(size_t)255;
        return p;
    };
    float* dinv = (float*)take((size_t)N_NODES * 4);
    int* row = (int*)take((size_t)(N_NODES + 1) * 4);
    int* col = (int*)take((size_t)N_EDGES * 4);
    u32* entries = (u32*)take((size_t)N_EDGES * 4);
    int* bcnt = (int*)take((size_t)NBUCK * 4);
    int* boff = (int*)take((size_t)(NBUCK + 1) * 4);
    int* bcur = (int*)take((size_t)NBUCK * 4);
    __half2* bufH = (__half2*)take((size_t)N_NODES * 128 * 2);  // fp16 g (layers 1-2)
    float* bufA = (float*)take((size_t)N_NODES * 128 * 4);      // h2 [N,128] then g3 [N,8]
    float* bufB = (float*)take((size_t)N_NODES * 64 * 4);       // h3 [N,64] then h4 [N,8]
    f16* Wth = (f16*)take((size_t)128 * 256 * 2);               // W1^T hi (k-major)
    f16* Wtl = (f16*)take((size_t)128 * 256 * 2);               // W1^T lo

    const int* srcp = eidx;            // edge_index[0]
    const int* dstp = eidx + N_EDGES;  // edge_index[1]

    const int scat_blocks = (N_EDGES + 8191) / 8192;  // 391

    hipMemsetAsync(bcnt, 0, (size_t)NBUCK * 4, stream);
    k_prepw<<<128, 256, 0, stream>>>(W1, Wth, Wtl);
    k_bhist<<<scat_blocks, 256, 0, stream>>>(dstp, bcnt);
    k_bscan<<<1, 256, 0, stream>>>(bcnt, boff, bcur, row);
    k_scatter<<<scat_blocks, 256, 0, stream>>>(srcp, dstp, bcur, entries);
    k_prep<<<NBUCK, 256, 0, stream>>>(entries, boff, row, dinv, col);

    k_gemm1<<<(N_NODES + 127) / 128, 256, 0, stream>>>(latent, hist, subg, W1, Wth, Wtl, dinv, bufH);
    k_aggh<128, 64><<<N_NODES / 4, 256, 0, stream>>>(bufH, row, col, dinv, b1, bufA);
    k_gemm2<<<N_NODES / 64, 256, 0, stream>>>(bufA, W2, dinv, bufH);
    k_aggh<64, 32><<<N_NODES / 8, 256, 0, stream>>>(bufH, row, col, dinv, b2, bufB);
    k_gemm3<<<(N_NODES + 255) / 256, 256, 0, stream>>>(bufB, W3, dinv, bufA);
    k_agg8<<<N_NODES / 32, 256, 0, stream>>>(bufA, row, col, dinv, b3, bufB);
    k_final<<<(N_NODES + 255) / 256, 256, 0, stream>>>(bufB, Wc, bc, outp);
}

// Round 2
// 817.306 us; speedup vs baseline: 1.0906x; 1.0906x over previous
//
#include <hip/hip_runtime.h>
#include <hip/hip_fp16.h>

// 3-layer GCN (fp32 compute): bucketed CSR build + (GEMM -> gather-aggregate) x3
// + final linear.
// Round 8: k_gemm1 restructured to be latency-tolerant. r7 was latency-bound
// (MfmaUtil 7%, VALUBusy 5%, HBM 9% -- nothing busy): 2 barriers per K-step +
// 16 L2-latency W loads serialized each iteration. Now: W (hi+lo f16, 128 KB)
// is staged to LDS ONCE per block with T2 XOR-swizzle (2-way banks on the
// 16-row-same-col ds_read_b128), X fragments go global->reg directly (the
// B-fragment layout is 8 consecutive floats of one row per lane -> 2 dwordx4,
// fully coalesced), fp32->hi/lo f16 split in VALU. 1024-thread blocks
// (16 waves, 256 nodes), ONE barrier total, waves free-run.

#define N_NODES 200000
#define N_EDGES 3200000
#define NBUCK 782            // ceil(200000/256)

static_assert(N_NODES % 64 == 0, "tiling");
static_assert((NBUCK - 1) * 256 < N_NODES && NBUCK * 256 >= N_NODES, "buckets");

typedef unsigned int u32;
typedef _Float16 f16;
typedef __attribute__((ext_vector_type(8))) _Float16 f16x8;
typedef __attribute__((ext_vector_type(4))) float f32x4;

// ---------------- bucket histogram ----------------

__global__ __launch_bounds__(256) void k_bhist(const int* __restrict__ dst,
                                               int* __restrict__ bcnt) {
    __shared__ int lh[NBUCK];
    int t = threadIdx.x;
    for (int b = t; b < NBUCK; b += 256) lh[b] = 0;
    __syncthreads();
    long e0 = (long)blockIdx.x * 8192;
    for (int k = 0; k < 32; ++k) {
        long e = e0 + k * 256 + t;
        if (e < N_EDGES) atomicAdd(&lh[dst[e] >> 8], 1);
    }
    __syncthreads();
    for (int b = t; b < NBUCK; b += 256)
        if (lh[b]) atomicAdd(&bcnt[b], lh[b]);
}

// ---------------- bucket scan (1 block) ----------------

__global__ __launch_bounds__(256) void k_bscan(const int* __restrict__ bcnt,
                                               int* __restrict__ boff,
                                               int* __restrict__ bcur,
                                               int* __restrict__ row) {
    __shared__ int sm[256];
    int t = threadIdx.x;
    int base = t * 4;
    int a0 = (base + 0 < NBUCK) ? bcnt[base + 0] : 0;
    int a1 = (base + 1 < NBUCK) ? bcnt[base + 1] : 0;
    int a2 = (base + 2 < NBUCK) ? bcnt[base + 2] : 0;
    int a3 = (base + 3 < NBUCK) ? bcnt[base + 3] : 0;
    int s = a0 + a1 + a2 + a3;
    sm[t] = s;
    __syncthreads();
    for (int o = 1; o < 256; o <<= 1) {
        int v = (t >= o) ? sm[t - o] : 0;
        __syncthreads();
        sm[t] += v;
        __syncthreads();
    }
    int excl = sm[t] - s;
    if (base + 0 < NBUCK) { boff[base + 0] = excl;               bcur[base + 0] = excl; }
    if (base + 1 < NBUCK) { boff[base + 1] = excl + a0;          bcur[base + 1] = excl + a0; }
    if (base + 2 < NBUCK) { boff[base + 2] = excl + a0 + a1;     bcur[base + 2] = excl + a0 + a1; }
    if (base + 3 < NBUCK) { boff[base + 3] = excl + a0 + a1 + a2; bcur[base + 3] = excl + a0 + a1 + a2; }
    if (t == 255) { boff[NBUCK] = N_EDGES; row[N_NODES] = N_EDGES; }
}

// ------------- chunked scatter: entries[p] = (src<<8)|dst_local -------------

__global__ __launch_bounds__(256) void k_scatter(const int* __restrict__ src,
                                                 const int* __restrict__ dst,
                                                 int* __restrict__ bcur,
                                                 u32* __restrict__ entries) {
    __shared__ int lh[NBUCK];
    __shared__ int base[NBUCK];
    __shared__ int lcur[NBUCK];
    int t = threadIdx.x;
    for (int b = t; b < NBUCK; b += 256) lh[b] = 0;
    __syncthreads();
    long e0 = (long)blockIdx.x * 8192;
    for (int k = 0; k < 32; ++k) {
        long e = e0 + k * 256 + t;
        if (e < N_EDGES) atomicAdd(&lh[dst[e] >> 8], 1);
    }
    __syncthreads();
    for (int b = t; b < NBUCK; b += 256) {
        base[b] = atomicAdd(&bcur[b], lh[b]);
        lcur[b] = 0;
    }
    __syncthreads();
    for (int k = 0; k < 32; ++k) {
        long e = e0 + k * 256 + t;
        if (e < N_EDGES) {
            int d = dst[e];
            int bkt = d >> 8;
            int p = base[bkt] + atomicAdd(&lcur[bkt], 1);
            entries[p] = ((u32)src[e] << 8) | (u32)(d & 255);
        }
    }
}

// --- per-bucket prep: deg/row/dinv + col fill, all L2-local to one block ----

__global__ __launch_bounds__(256) void k_prep(const u32* __restrict__ entries,
                                              const int* __restrict__ boff,
                                              int* __restrict__ row,
                                              float* __restrict__ dinv,
                                              int* __restrict__ col) {
    __shared__ int lh[256];
    __shared__ int sc[256];
    __shared__ int cur[256];
    const int b = blockIdx.x, t = threadIdx.x;
    const int s = boff[b], e = boff[b + 1];
    const int cnt = e - s;
    lh[t] = 0;
    __syncthreads();
    for (int i = t; i < cnt; i += 256) atomicAdd(&lh[entries[s + i] & 255], 1);
    __syncthreads();
    int my = lh[t];
    sc[t] = my;
    __syncthreads();
    for (int o = 1; o < 256; o <<= 1) {
        int v = (t >= o) ? sc[t - o] : 0;
        __syncthreads();
        sc[t] += v;
        __syncthreads();
    }
    int excl = sc[t] - my;
    int node = b * 256 + t;
    if (node < N_NODES) {
        row[node] = s + excl;
        dinv[node] = rsqrtf((float)(my + 1));  // +1 self-loop
    }
    cur[t] = s + excl;
    __syncthreads();
    for (int i = t; i < cnt; i += 256) {
        u32 en = entries[s + i];
        int p = atomicAdd(&cur[en & 255], 1);
        col[p] = (int)(en >> 8);
    }
}

// ------- W1 pre-split/transpose: Wth/Wtl[f][k] f16 hi/lo, k-major -----------

__global__ __launch_bounds__(256) void k_prepw(const float* __restrict__ W,
                                               f16* __restrict__ Wth,
                                               f16* __restrict__ Wtl) {
    int t = blockIdx.x * 256 + threadIdx.x;  // 0..32767
    int k = t >> 7;                          // 0..255 (tail rows 256/257 stay fp32)
    int f = t & 127;
    float w = W[k * 128 + f];
    f16 hi = (f16)w;
    f16 lo = (f16)(w - (float)hi);
    Wth[f * 256 + k] = hi;
    Wtl[f * 256 + k] = lo;
}

// ------- GEMM layer 1 (MFMA): [N,258]x[258,128], epilogue g = dinv*h -> fp16
// 1024 threads = 16 waves, 256 nodes/block, 16 nodes/wave. W hi+lo in LDS
// (128 KB, XOR-swizzled), staged once; X fragments global->reg (8 consecutive
// floats/lane); no per-K-step barriers. 3-term split-f16 = ~fp32 precision.

__global__ __launch_bounds__(1024) void k_gemm1(const float* __restrict__ X,
                                                const float* __restrict__ hist,
                                                const float* __restrict__ subg,
                                                const float* __restrict__ W,
                                                const f16* __restrict__ Wth,
                                                const f16* __restrict__ Wtl,
                                                const float* __restrict__ dinv,
                                                __half2* __restrict__ g1) {
    __shared__ f16 Ws[2][128 * 256];   // [hi/lo][row*256+k], byte^((row&7)<<4)
    const int t = threadIdx.x;

    // ---- stage W once (swizzled writes, coalesced global reads) ----
    {
        const int r = t >> 3;          // feat row 0..127
        const int seg = t & 7;         // 32 halves each
        const f16* gh = Wth + r * 256 + seg * 32;
        const f16* gl = Wtl + r * 256 + seg * 32;
        const int sw = (r & 7) << 4;
        const int base = r * 512 + seg * 64;   // byte offset, 16B-granular
        char* wsh = (char*)&Ws[0][0];
        char* wsl = (char*)&Ws[1][0];
#pragma unroll
        for (int q = 0; q < 4; ++q) {
            *(f16x8*)(wsh + ((base + q * 16) ^ sw)) = *(const f16x8*)(gh + q * 8);
            *(f16x8*)(wsl + ((base + q * 16) ^ sw)) = *(const f16x8*)(gl + q * 8);
        }
    }

    const int wv = t >> 6;          // wave 0..15
    const int l = t & 63;
    const int l15 = l & 15;         // node within wave / D column
    const int lk = l >> 4;          // k-chunk 0..3 (8 halves each)
    const int nb = blockIdx.x * 256;
    const int node = nb + wv * 16 + l15;
    const int xrow = node < N_NODES ? node : N_NODES - 1;  // clamp (stores guarded)
    const float* xbase = X + (size_t)xrow * 256 + lk * 8;

    f32x4 acc[8];
#pragma unroll
    for (int fb = 0; fb < 8; ++fb) acc[fb] = (f32x4){0.f, 0.f, 0.f, 0.f};

    // prefetch K-tile 0 (in flight across the staging barrier)
    float4 pa = *(const float4*)(xbase + 0);
    float4 pb = *(const float4*)(xbase + 4);

    __syncthreads();  // W staged -- the only barrier

    const char* wsh = (const char*)&Ws[0][0];
    const char* wsl = (const char*)&Ws[1][0];
    const int sw = (l15 & 7) << 4;  // row&7 == l15&7 for every fb

    for (int kc = 0; kc < 256; kc += 32) {
        float xs[8] = {pa.x, pa.y, pa.z, pa.w, pb.x, pb.y, pb.z, pb.w};
        if (kc + 32 < 256) {  // issue next-tile loads before compute
            pa = *(const float4*)(xbase + kc + 32);
            pb = *(const float4*)(xbase + kc + 36);
        }
        union { f16 h[8]; f16x8 v; } H, L;
#pragma unroll
        for (int i = 0; i < 8; ++i) {
            f16 h = (f16)xs[i];
            H.h[i] = h;
            L.h[i] = (f16)(xs[i] - (float)h);
        }
        f16x8 xh = H.v, xl = L.v;

        const int koff = ((kc + lk * 8) * 2) ^ sw;  // swizzled within-row byte off
#pragma unroll
        for (int fb = 0; fb < 8; ++fb) {
            const int off = (fb * 16 + l15) * 512 + koff;
            f16x8 wh = *(const f16x8*)(wsh + off);
            f16x8 wl = *(const f16x8*)(wsl + off);
            acc[fb] = __builtin_amdgcn_mfma_f32_16x16x32_f16(wh, xh, acc[fb], 0, 0, 0);
            acc[fb] = __builtin_amdgcn_mfma_f32_16x16x32_f16(wh, xl, acc[fb], 0, 0, 0);
            acc[fb] = __builtin_amdgcn_mfma_f32_16x16x32_f16(wl, xh, acc[fb], 0, 0, 0);
        }
    }

    // epilogue: K tail rows 256 (hist), 257 (subg) in exact fp32; scale dinv.
    const bool ok = node < N_NODES;
    const float hh = hist[xrow];
    const float ss = subg[xrow];
    const float dv = dinv[xrow];
    char* orow = (char*)g1 + (size_t)node * 256;
#pragma unroll
    for (int fb = 0; fb < 8; ++fb) {
        const int f0 = fb * 16 + lk * 4;  // 4 consecutive feats per lane
        float4 w6 = *(const float4*)(W + 256 * 128 + f0);
        float4 w7 = *(const float4*)(W + 257 * 128 + f0);
        union { f16 h[4]; float2 v; } o;
        o.h[0] = (f16)((acc[fb][0] + hh * w6.x + ss * w7.x) * dv);
        o.h[1] = (f16)((acc[fb][1] + hh * w6.y + ss * w7.y) * dv);
        o.h[2] = (f16)((acc[fb][2] + hh * w6.z + ss * w7.z) * dv);
        o.h[3] = (f16)((acc[fb][3] + hh * w6.w + ss * w7.w) * dv);
        if (ok) *(float2*)(orow + fb * 32 + lk * 8) = o.v;
    }
}

// ------- GEMM layer 2: [N,128]x[128,64] fp32, epilogue g = dinv*h -> fp16 ----

__global__ __launch_bounds__(256) void k_gemm2(const float* __restrict__ Xin,
                                               const float* __restrict__ W,
                                               const float* __restrict__ dinv,
                                               __half2* __restrict__ g2) {
    __shared__ float Xs[64][33];
    __shared__ float Ws[32][68];
    const int t = threadIdx.x;
    const int nb = blockIdx.x * 64;
    const int fi = t & 15;
    const int ni = t >> 4;
    const int lxn = t >> 2;
    const int lxk = (t & 3) * 8;
    const int lwk = t >> 3;
    const int lwf = (t & 7) * 8;

    float acc[4][4];
#pragma unroll
    for (int n = 0; n < 4; ++n)
#pragma unroll
        for (int f = 0; f < 4; ++f) acc[n][f] = 0.f;

    for (int kc = 0; kc < 128; kc += 32) {
        const float* xp = Xin + (size_t)(nb + lxn) * 128 + kc + lxk;
        float4 xa = *(const float4*)xp;
        float4 xb = *(const float4*)(xp + 4);
        Xs[lxn][lxk + 0] = xa.x;
        Xs[lxn][lxk + 1] = xa.y;
        Xs[lxn][lxk + 2] = xa.z;
        Xs[lxn][lxk + 3] = xa.w;
        Xs[lxn][lxk + 4] = xb.x;
        Xs[lxn][lxk + 5] = xb.y;
        Xs[lxn][lxk + 6] = xb.z;
        Xs[lxn][lxk + 7] = xb.w;

        const float* wp = W + (size_t)(kc + lwk) * 64 + lwf;
        float4* wsp = (float4*)&Ws[lwk][lwf];
        wsp[0] = *(const float4*)(wp + 0);
        wsp[1] = *(const float4*)(wp + 4);
        __syncthreads();

#pragma unroll
        for (int kk = 0; kk < 32; ++kk) {
            float4 wv = *(const float4*)&Ws[kk][fi * 4];
#pragma unroll
            for (int n = 0; n < 4; ++n) {
                float xv = Xs[ni * 4 + n][kk];
                acc[n][0] += xv * wv.x;
                acc[n][1] += xv * wv.y;
                acc[n][2] += xv * wv.z;
                acc[n][3] += xv * wv.w;
            }
        }
        __syncthreads();
    }

#pragma unroll
    for (int n = 0; n < 4; ++n) {
        float dv = dinv[nb + ni * 4 + n];
        float2 pk;
        __half2* ph = (__half2*)&pk;
#pragma unroll
        for (int k = 0; k < 2; ++k) {
            __half2 h;
            h.x = __float2half_rn(acc[n][2 * k + 0] * dv);
            h.y = __float2half_rn(acc[n][2 * k + 1] * dv);
            ph[k] = h;
        }
        *(float2*)(g2 + (size_t)(nb + ni * 4 + n) * 32 + fi * 2) = pk;
    }
}

// ------- GEMM layer 3: [N,64]x[64,8], epilogue g = dinv*h (fp32) -------------

__global__ __launch_bounds__(256) void k_gemm3(const float* __restrict__ Xin,
                                               const float* __restrict__ W,
                                               const float* __restrict__ dinv,
                                               float* __restrict__ g3) {
    __shared__ float Ws[512];
    int t = threadIdx.x;
    Ws[t] = W[t];
    Ws[t + 256] = W[t + 256];
    __syncthreads();
    int i = blockIdx.x * 256 + t;
    if (i >= N_NODES) return;
    const float4* xp = (const float4*)(Xin + (size_t)i * 64);
    float acc[8];
#pragma unroll
    for (int f = 0; f < 8; ++f) acc[f] = 0.f;
#pragma unroll
    for (int k4 = 0; k4 < 16; ++k4) {
        float4 xv = xp[k4];
        float xs[4] = {xv.x, xv.y, xv.z, xv.w};
#pragma unroll
        for (int q = 0; q < 4; ++q) {
            int k = k4 * 4 + q;
            float4 w0 = *(const float4*)&Ws[k * 8];
            float4 w1 = *(const float4*)&Ws[k * 8 + 4];
            acc[0] += xs[q] * w0.x;
            acc[1] += xs[q] * w0.y;
            acc[2] += xs[q] * w0.z;
            acc[3] += xs[q] * w0.w;
            acc[4] += xs[q] * w1.x;
            acc[5] += xs[q] * w1.y;
            acc[6] += xs[q] * w1.z;
            acc[7] += xs[q] * w1.w;
        }
    }
    float dv = dinv[i];
    float* op = g3 + (size_t)i * 8;
    *(float4*)op = make_float4(acc[0] * dv, acc[1] * dv, acc[2] * dv, acc[3] * dv);
    *(float4*)(op + 4) = make_float4(acc[4] * dv, acc[5] * dv, acc[6] * dv, acc[7] * dv);
}

// ------- aggregation (fp16 payload): out[i] = relu(dinv_i*(sum_j g_j + g_i)+b)

template <int F, int TPN>
__global__ __launch_bounds__(256) void k_aggh(const __half2* __restrict__ g,
                                              const int* __restrict__ row,
                                              const int* __restrict__ col,
                                              const float* __restrict__ dinv,
                                              const float* __restrict__ bias,
                                              float* __restrict__ out) {
    constexpr int H2 = F / 2;
    static_assert(TPN == H2, "one half2 per lane");
    constexpr int NPB = 256 / TPN;
    const int t = threadIdx.x;
    const int node = blockIdx.x * NPB + t / TPN;
    const int lane = t % TPN;

    float ax = 0.f, ay = 0.f;
    const int s = row[node];
    const int e = row[node + 1];
    int idx = s;
    for (; idx + 8 <= e; idx += 8) {
        int j[8];
#pragma unroll
        for (int u = 0; u < 8; ++u) j[u] = col[idx + u];
        __half2 h[8];
#pragma unroll
        for (int u = 0; u < 8; ++u) h[u] = g[(size_t)j[u] * H2 + lane];
#pragma unroll
        for (int u = 0; u < 8; ++u) {
            float2 f = __half22float2(h[u]);
            ax += f.x;
            ay += f.y;
        }
    }
    for (; idx < e; ++idx) {
        float2 f = __half22float2(g[(size_t)col[idx] * H2 + lane]);
        ax += f.x;
        ay += f.y;
    }
    float2 fs = __half22float2(g[(size_t)node * H2 + lane]);  // self-loop
    const float di = dinv[node];
    float2 b = *(const float2*)(bias + lane * 2);
    float2 o;
    o.x = fmaxf(di * (ax + fs.x) + b.x, 0.f);
    o.y = fmaxf(di * (ay + fs.y) + b.y, 0.f);
    *(float2*)(out + (size_t)node * F + lane * 2) = o;
}

// ------- aggregation layer 3 (fp32, F=8, pre-scaled payload) -----------------

__global__ __launch_bounds__(256) void k_agg8(const float* __restrict__ g,
                                              const int* __restrict__ row,
                                              const int* __restrict__ col,
                                              const float* __restrict__ dinv,
                                              const float* __restrict__ bias,
                                              float* __restrict__ out) {
    const int t = threadIdx.x;
    const int node = blockIdx.x * 32 + t / 8;
    const int lane = t & 7;
    float acc = 0.f;
    const int s = row[node];
    const int e = row[node + 1];
    int idx = s;
    for (; idx + 8 <= e; idx += 8) {
        int j[8];
#pragma unroll
        for (int u = 0; u < 8; ++u) j[u] = col[idx + u];
        float v[8];
#pragma unroll
        for (int u = 0; u < 8; ++u) v[u] = g[(size_t)j[u] * 8 + lane];
#pragma unroll
        for (int u = 0; u < 8; ++u) acc += v[u];
    }
    for (; idx < e; ++idx) acc += g[(size_t)col[idx] * 8 + lane];
    acc += g[(size_t)node * 8 + lane];  // self-loop
    out[(size_t)node * 8 + lane] = fmaxf(dinv[node] * acc + bias[lane], 0.f);
}

// ---------------- final linear: [N,8]x[8,3] + bc -----------------------------

__global__ __launch_bounds__(256) void k_final(const float* __restrict__ h,
                                               const float* __restrict__ Wc,
                                               const float* __restrict__ bc,
                                               float* __restrict__ out) {
    int i = blockIdx.x * 256 + threadIdx.x;
    if (i >= N_NODES) return;
    const float4* xp = (const float4*)(h + (size_t)i * 8);
    float4 x0 = xp[0], x1 = xp[1];
    float xs[8] = {x0.x, x0.y, x0.z, x0.w, x1.x, x1.y, x1.z, x1.w};
    float o0 = bc[0], o1 = bc[1], o2 = bc[2];
#pragma unroll
    for (int k = 0; k < 8; ++k) {
        o0 += xs[k] * Wc[k * 3 + 0];
        o1 += xs[k] * Wc[k * 3 + 1];
        o2 += xs[k] * Wc[k * 3 + 2];
    }
    out[(size_t)i * 3 + 0] = o0;
    out[(size_t)i * 3 + 1] = o1;
    out[(size_t)i * 3 + 2] = o2;
}

// ---------------- launch -----------------------------------------------------

extern "C" void kernel_launch(void* const* d_in, const int* in_sizes, int n_in,
                              void* d_out, int out_size, void* d_ws, size_t ws_size,
                              hipStream_t stream) {
    const float* latent = (const float*)d_in[0];
    const float* hist = (const float*)d_in[1];
    const float* subg = (const float*)d_in[2];
    const int* eidx = (const int*)d_in[3];
    const float* W1 = (const float*)d_in[4];
    const float* b1 = (const float*)d_in[5];
    const float* W2 = (const float*)d_in[6];
    const float* b2 = (const float*)d_in[7];
    const float* W3 = (const float*)d_in[8];
    const float* b3 = (const float*)d_in[9];
    const float* Wc = (const float*)d_in[10];
    const float* bc = (const float*)d_in[11];
    float* outp = (float*)d_out;

    char* ws = (char*)d_ws;
    size_t off = 0;
    auto take = [&](size_t bytes) -> void* {
        void* p = ws + off;
        off += (bytes + 255) & ~(size_t)255;
        return p;
    };
    float* dinv = (float*)take((size_t)N_NODES * 4);
    int* row = (int*)take((size_t)(N_NODES + 1) * 4);
    int* col = (int*)take((size_t)N_EDGES * 4);
    u32* entries = (u32*)take((size_t)N_EDGES * 4);
    int* bcnt = (int*)take((size_t)NBUCK * 4);
    int* boff = (int*)take((size_t)(NBUCK + 1) * 4);
    int* bcur = (int*)take((size_t)NBUCK * 4);
    __half2* bufH = (__half2*)take((size_t)N_NODES * 128 * 2);  // fp16 g (layers 1-2)
    float* bufA = (float*)take((size_t)N_NODES * 128 * 4);      // h2 [N,128] then g3 [N,8]
    float* bufB = (float*)take((size_t)N_NODES * 64 * 4);       // h3 [N,64] then h4 [N,8]
    f16* Wth = (f16*)take((size_t)128 * 256 * 2);               // W1^T hi (k-major)
    f16* Wtl = (f16*)take((size_t)128 * 256 * 2);               // W1^T lo

    const int* srcp = eidx;            // edge_index[0]
    const int* dstp = eidx + N_EDGES;  // edge_index[1]

    const int scat_blocks = (N_EDGES + 8191) / 8192;  // 391

    hipMemsetAsync(bcnt, 0, (size_t)NBUCK * 4, stream);
    k_prepw<<<128, 256, 0, stream>>>(W1, Wth, Wtl);
    k_bhist<<<scat_blocks, 256, 0, stream>>>(dstp, bcnt);
    k_bscan<<<1, 256, 0, stream>>>(bcnt, boff, bcur, row);
    k_scatter<<<scat_blocks, 256, 0, stream>>>(srcp, dstp, bcur, entries);
    k_prep<<<NBUCK, 256, 0, stream>>>(entries, boff, row, dinv, col);

    k_gemm1<<<(N_NODES + 255) / 256, 1024, 0, stream>>>(latent, hist, subg, W1, Wth, Wtl, dinv, bufH);
    k_aggh<128, 64><<<N_NODES / 4, 256, 0, stream>>>(bufH, row, col, dinv, b1, bufA);
    k_gemm2<<<N_NODES / 64, 256, 0, stream>>>(bufA, W2, dinv, bufH);
    k_aggh<64, 32><<<N_NODES / 8, 256, 0, stream>>>(bufH, row, col, dinv, b2, bufB);
    k_gemm3<<<(N_NODES + 255) / 256, 256, 0, stream>>>(bufB, W3, dinv, bufA);
    k_agg8<<<N_NODES / 32, 256, 0, stream>>>(bufA, row, col, dinv, b3, bufB);
    k_final<<<(N_NODES + 255) / 256, 256, 0, stream>>>(bufB, Wc, bc, outp);
}

// Round 3
// 737.304 us; speedup vs baseline: 1.2089x; 1.1085x over previous
//
#include <hip/hip_runtime.h>
#include <hip/hip_fp16.h>

// 3-layer GCN (fp32 compute): bucketed CSR build + gemm1 + fused
// (aggregate -> GEMM) pairs.
// Round 9: fused k_ag2 (agg1+gemm2), k_ag3 (agg2+gemm3), k_agf (agg3+final).
// Eliminates the h2 [N,128] f32 (204.8 MB), h3 [N,64] f32 (102.4 MB) and
// h4 [N,8] (12.8 MB) HBM round-trips: aggregated rows pass through LDS.
// k_ag2's GEMM phase uses the same verified 3-term split-f16 MFMA as gemm1
// (W2 pre-split/transposed by k_prepw2); aggregated h-rows are split hi/lo
// f16 into LDS [64][136] (272 B stride -> b128 reads at the 8-cyc floor).

#define N_NODES 200000
#define N_EDGES 3200000
#define NBUCK 782            // ceil(200000/256)

static_assert(N_NODES % 64 == 0, "tiling");
static_assert((NBUCK - 1) * 256 < N_NODES && NBUCK * 256 >= N_NODES, "buckets");

typedef unsigned int u32;
typedef _Float16 f16;
typedef __attribute__((ext_vector_type(8))) _Float16 f16x8;
typedef __attribute__((ext_vector_type(4))) float f32x4;

// ---------------- bucket histogram ----------------

__global__ __launch_bounds__(256) void k_bhist(const int* __restrict__ dst,
                                               int* __restrict__ bcnt) {
    __shared__ int lh[NBUCK];
    int t = threadIdx.x;
    for (int b = t; b < NBUCK; b += 256) lh[b] = 0;
    __syncthreads();
    long e0 = (long)blockIdx.x * 8192;
    for (int k = 0; k < 32; ++k) {
        long e = e0 + k * 256 + t;
        if (e < N_EDGES) atomicAdd(&lh[dst[e] >> 8], 1);
    }
    __syncthreads();
    for (int b = t; b < NBUCK; b += 256)
        if (lh[b]) atomicAdd(&bcnt[b], lh[b]);
}

// ---------------- bucket scan (1 block) ----------------

__global__ __launch_bounds__(256) void k_bscan(const int* __restrict__ bcnt,
                                               int* __restrict__ boff,
                                               int* __restrict__ bcur,
                                               int* __restrict__ row) {
    __shared__ int sm[256];
    int t = threadIdx.x;
    int base = t * 4;
    int a0 = (base + 0 < NBUCK) ? bcnt[base + 0] : 0;
    int a1 = (base + 1 < NBUCK) ? bcnt[base + 1] : 0;
    int a2 = (base + 2 < NBUCK) ? bcnt[base + 2] : 0;
    int a3 = (base + 3 < NBUCK) ? bcnt[base + 3] : 0;
    int s = a0 + a1 + a2 + a3;
    sm[t] = s;
    __syncthreads();
    for (int o = 1; o < 256; o <<= 1) {
        int v = (t >= o) ? sm[t - o] : 0;
        __syncthreads();
        sm[t] += v;
        __syncthreads();
    }
    int excl = sm[t] - s;
    if (base + 0 < NBUCK) { boff[base + 0] = excl;               bcur[base + 0] = excl; }
    if (base + 1 < NBUCK) { boff[base + 1] = excl + a0;          bcur[base + 1] = excl + a0; }
    if (base + 2 < NBUCK) { boff[base + 2] = excl + a0 + a1;     bcur[base + 2] = excl + a0 + a1; }
    if (base + 3 < NBUCK) { boff[base + 3] = excl + a0 + a1 + a2; bcur[base + 3] = excl + a0 + a1 + a2; }
    if (t == 255) { boff[NBUCK] = N_EDGES; row[N_NODES] = N_EDGES; }
}

// ------------- chunked scatter: entries[p] = (src<<8)|dst_local -------------

__global__ __launch_bounds__(256) void k_scatter(const int* __restrict__ src,
                                                 const int* __restrict__ dst,
                                                 int* __restrict__ bcur,
                                                 u32* __restrict__ entries) {
    __shared__ int lh[NBUCK];
    __shared__ int base[NBUCK];
    __shared__ int lcur[NBUCK];
    int t = threadIdx.x;
    for (int b = t; b < NBUCK; b += 256) lh[b] = 0;
    __syncthreads();
    long e0 = (long)blockIdx.x * 8192;
    for (int k = 0; k < 32; ++k) {
        long e = e0 + k * 256 + t;
        if (e < N_EDGES) atomicAdd(&lh[dst[e] >> 8], 1);
    }
    __syncthreads();
    for (int b = t; b < NBUCK; b += 256) {
        base[b] = atomicAdd(&bcur[b], lh[b]);
        lcur[b] = 0;
    }
    __syncthreads();
    for (int k = 0; k < 32; ++k) {
        long e = e0 + k * 256 + t;
        if (e < N_EDGES) {
            int d = dst[e];
            int bkt = d >> 8;
            int p = base[bkt] + atomicAdd(&lcur[bkt], 1);
            entries[p] = ((u32)src[e] << 8) | (u32)(d & 255);
        }
    }
}

// --- per-bucket prep: deg/row/dinv + col fill, all L2-local to one block ----

__global__ __launch_bounds__(256) void k_prep(const u32* __restrict__ entries,
                                              const int* __restrict__ boff,
                                              int* __restrict__ row,
                                              float* __restrict__ dinv,
                                              int* __restrict__ col) {
    __shared__ int lh[256];
    __shared__ int sc[256];
    __shared__ int cur[256];
    const int b = blockIdx.x, t = threadIdx.x;
    const int s = boff[b], e = boff[b + 1];
    const int cnt = e - s;
    lh[t] = 0;
    __syncthreads();
    for (int i = t; i < cnt; i += 256) atomicAdd(&lh[entries[s + i] & 255], 1);
    __syncthreads();
    int my = lh[t];
    sc[t] = my;
    __syncthreads();
    for (int o = 1; o < 256; o <<= 1) {
        int v = (t >= o) ? sc[t - o] : 0;
        __syncthreads();
        sc[t] += v;
        __syncthreads();
    }
    int excl = sc[t] - my;
    int node = b * 256 + t;
    if (node < N_NODES) {
        row[node] = s + excl;
        dinv[node] = rsqrtf((float)(my + 1));  // +1 self-loop
    }
    cur[t] = s + excl;
    __syncthreads();
    for (int i = t; i < cnt; i += 256) {
        u32 en = entries[s + i];
        int p = atomicAdd(&cur[en & 255], 1);
        col[p] = (int)(en >> 8);
    }
}

// ------- W1 pre-split/transpose: Wth/Wtl[f][k] f16 hi/lo, k-major -----------

__global__ __launch_bounds__(256) void k_prepw(const float* __restrict__ W,
                                               f16* __restrict__ Wth,
                                               f16* __restrict__ Wtl) {
    int t = blockIdx.x * 256 + threadIdx.x;  // 0..32767
    int k = t >> 7;                          // 0..255 (tail rows 256/257 stay fp32)
    int f = t & 127;
    float w = W[k * 128 + f];
    f16 hi = (f16)w;
    f16 lo = (f16)(w - (float)hi);
    Wth[f * 256 + k] = hi;
    Wtl[f * 256 + k] = lo;
}

// ------- W2 pre-split/transpose: [128][64] -> hi/lo f16 [64][128] k-major ----

__global__ __launch_bounds__(256) void k_prepw2(const float* __restrict__ W2,
                                                f16* __restrict__ Wh,
                                                f16* __restrict__ Wl) {
    int t = blockIdx.x * 256 + threadIdx.x;  // 0..8191
    int k = t >> 6;                          // 0..127
    int f = t & 63;
    float w = W2[k * 64 + f];
    f16 hi = (f16)w;
    Wh[f * 128 + k] = hi;
    Wl[f * 128 + k] = (f16)(w - (float)hi);
}

// ------- GEMM layer 1 (MFMA): [N,258]x[258,128], epilogue g = dinv*h -> fp16
// 1024 threads = 16 waves, 256 nodes/block, 16 nodes/wave. W hi+lo in LDS
// (128 KB, XOR-swizzled), staged once; X fragments global->reg (8 consecutive
// floats/lane); no per-K-step barriers. 3-term split-f16 = ~fp32 precision.

__global__ __launch_bounds__(1024) void k_gemm1(const float* __restrict__ X,
                                                const float* __restrict__ hist,
                                                const float* __restrict__ subg,
                                                const float* __restrict__ W,
                                                const f16* __restrict__ Wth,
                                                const f16* __restrict__ Wtl,
                                                const float* __restrict__ dinv,
                                                __half2* __restrict__ g1) {
    __shared__ f16 Ws[2][128 * 256];   // [hi/lo][row*256+k], byte^((row&7)<<4)
    const int t = threadIdx.x;

    // ---- stage W once (swizzled writes, coalesced global reads) ----
    {
        const int r = t >> 3;          // feat row 0..127
        const int seg = t & 7;         // 32 halves each
        const f16* gh = Wth + r * 256 + seg * 32;
        const f16* gl = Wtl + r * 256 + seg * 32;
        const int sw = (r & 7) << 4;
        const int base = r * 512 + seg * 64;   // byte offset, 16B-granular
        char* wsh = (char*)&Ws[0][0];
        char* wsl = (char*)&Ws[1][0];
#pragma unroll
        for (int q = 0; q < 4; ++q) {
            *(f16x8*)(wsh + ((base + q * 16) ^ sw)) = *(const f16x8*)(gh + q * 8);
            *(f16x8*)(wsl + ((base + q * 16) ^ sw)) = *(const f16x8*)(gl + q * 8);
        }
    }

    const int wv = t >> 6;          // wave 0..15
    const int l = t & 63;
    const int l15 = l & 15;         // node within wave / D column
    const int lk = l >> 4;          // k-chunk 0..3 (8 halves each)
    const int nb = blockIdx.x * 256;
    const int node = nb + wv * 16 + l15;
    const int xrow = node < N_NODES ? node : N_NODES - 1;  // clamp (stores guarded)
    const float* xbase = X + (size_t)xrow * 256 + lk * 8;

    f32x4 acc[8];
#pragma unroll
    for (int fb = 0; fb < 8; ++fb) acc[fb] = (f32x4){0.f, 0.f, 0.f, 0.f};

    // prefetch K-tile 0 (in flight across the staging barrier)
    float4 pa = *(const float4*)(xbase + 0);
    float4 pb = *(const float4*)(xbase + 4);

    __syncthreads();  // W staged -- the only barrier

    const char* wsh = (const char*)&Ws[0][0];
    const char* wsl = (const char*)&Ws[1][0];
    const int sw = (l15 & 7) << 4;  // row&7 == l15&7 for every fb

    for (int kc = 0; kc < 256; kc += 32) {
        float xs[8] = {pa.x, pa.y, pa.z, pa.w, pb.x, pb.y, pb.z, pb.w};
        if (kc + 32 < 256) {  // issue next-tile loads before compute
            pa = *(const float4*)(xbase + kc + 32);
            pb = *(const float4*)(xbase + kc + 36);
        }
        union { f16 h[8]; f16x8 v; } H, L;
#pragma unroll
        for (int i = 0; i < 8; ++i) {
            f16 h = (f16)xs[i];
            H.h[i] = h;
            L.h[i] = (f16)(xs[i] - (float)h);
        }
        f16x8 xh = H.v, xl = L.v;

        const int koff = ((kc + lk * 8) * 2) ^ sw;  // swizzled within-row byte off
#pragma unroll
        for (int fb = 0; fb < 8; ++fb) {
            const int off = (fb * 16 + l15) * 512 + koff;
            f16x8 wh = *(const f16x8*)(wsh + off);
            f16x8 wl = *(const f16x8*)(wsl + off);
            acc[fb] = __builtin_amdgcn_mfma_f32_16x16x32_f16(wh, xh, acc[fb], 0, 0, 0);
            acc[fb] = __builtin_amdgcn_mfma_f32_16x16x32_f16(wh, xl, acc[fb], 0, 0, 0);
            acc[fb] = __builtin_amdgcn_mfma_f32_16x16x32_f16(wl, xh, acc[fb], 0, 0, 0);
        }
    }

    // epilogue: K tail rows 256 (hist), 257 (subg) in exact fp32; scale dinv.
    const bool ok = node < N_NODES;
    const float hh = hist[xrow];
    const float ss = subg[xrow];
    const float dv = dinv[xrow];
    char* orow = (char*)g1 + (size_t)node * 256;
#pragma unroll
    for (int fb = 0; fb < 8; ++fb) {
        const int f0 = fb * 16 + lk * 4;  // 4 consecutive feats per lane
        float4 w6 = *(const float4*)(W + 256 * 128 + f0);
        float4 w7 = *(const float4*)(W + 257 * 128 + f0);
        union { f16 h[4]; float2 v; } o;
        o.h[0] = (f16)((acc[fb][0] + hh * w6.x + ss * w7.x) * dv);
        o.h[1] = (f16)((acc[fb][1] + hh * w6.y + ss * w7.y) * dv);
        o.h[2] = (f16)((acc[fb][2] + hh * w6.z + ss * w7.z) * dv);
        o.h[3] = (f16)((acc[fb][3] + hh * w6.w + ss * w7.w) * dv);
        if (ok) *(float2*)(orow + fb * 32 + lk * 8) = o.v;
    }
}

// ------- fused agg1 + gemm2: h2 = relu(dinv*(sum g1)+b1); g2 = dinv*(h2@W2)
// 1024 threads, 64 nodes/block. Phase A: 16 waves aggregate 4 nodes each,
// split hi/lo f16 into LDS [64][136] (272 B stride: b128 reads at 8-cyc
// floor). Phase B: 16 waves, one 16x16 MFMA tile each (K=128, 3-term split).

__global__ __launch_bounds__(1024) void k_ag2(const __half2* __restrict__ g,
                                              const int* __restrict__ row,
                                              const int* __restrict__ col,
                                              const float* __restrict__ dinv,
                                              const float* __restrict__ bias,
                                              const f16* __restrict__ W2hg,
                                              const f16* __restrict__ W2lg,
                                              __half2* __restrict__ g2) {
    __shared__ f16 Xh[64][136];
    __shared__ f16 Xl[64][136];
    __shared__ f16 Wh[64][136];
    __shared__ f16 Wl[64][136];
    const int t = threadIdx.x;
    const int nb = blockIdx.x * 64;

    // stage W2 hi/lo (once)
    {
        const int r = t >> 4;          // 0..63
        const int sg = (t & 15) * 8;   // 8 halves
        *(f16x8*)&Wh[r][sg] = *(const f16x8*)(W2hg + r * 128 + sg);
        *(f16x8*)&Wl[r][sg] = *(const f16x8*)(W2lg + r * 128 + sg);
    }

    // ---- phase A: aggregate (lane owns feats 2l, 2l+1) ----
    const int wv = t >> 6;
    const int l = t & 63;
    for (int i = 0; i < 4; ++i) {
        const int nloc = wv * 4 + i;
        const int node = nb + nloc;
        float ax = 0.f, ay = 0.f;
        const int s = row[node];
        const int e = row[node + 1];
        int idx = s;
        for (; idx + 8 <= e; idx += 8) {
            int j[8];
#pragma unroll
            for (int u = 0; u < 8; ++u) j[u] = col[idx + u];
            __half2 h[8];
#pragma unroll
            for (int u = 0; u < 8; ++u) h[u] = g[(size_t)j[u] * 64 + l];
#pragma unroll
            for (int u = 0; u < 8; ++u) {
                float2 f2 = __half22float2(h[u]);
                ax += f2.x;
                ay += f2.y;
            }
        }
        for (; idx + 2 <= e; idx += 2) {
            int j0 = col[idx], j1 = col[idx + 1];
            float2 f0 = __half22float2(g[(size_t)j0 * 64 + l]);
            float2 f1 = __half22float2(g[(size_t)j1 * 64 + l]);
            ax += f0.x + f1.x;
            ay += f0.y + f1.y;
        }
        if (idx < e) {
            float2 f2 = __half22float2(g[(size_t)col[idx] * 64 + l]);
            ax += f2.x;
            ay += f2.y;
        }
        float2 fs = __half22float2(g[(size_t)node * 64 + l]);  // self-loop
        const float di = dinv[node];
        float2 b = *(const float2*)(bias + l * 2);
        float hx = fmaxf(di * (ax + fs.x) + b.x, 0.f);
        float hy = fmaxf(di * (ay + fs.y) + b.y, 0.f);
        f16 hxh = (f16)hx, hyh = (f16)hy;
        union { f16 h[2]; u32 u; } uh, ul;
        uh.h[0] = hxh;
        uh.h[1] = hyh;
        ul.h[0] = (f16)(hx - (float)hxh);
        ul.h[1] = (f16)(hy - (float)hyh);
        *(u32*)&Xh[nloc][l * 2] = uh.u;
        *(u32*)&Xl[nloc][l * 2] = ul.u;
    }
    __syncthreads();

    // ---- phase B: 16 waves x one 16x16 MFMA tile, K=128 ----
    const int l15 = l & 15;
    const int lk = l >> 4;
    const int nw = wv & 3;    // node tile
    const int fw = wv >> 2;   // feat tile
    f32x4 acc = (f32x4){0.f, 0.f, 0.f, 0.f};
#pragma unroll
    for (int kc = 0; kc < 128; kc += 32) {
        f16x8 xh = *(const f16x8*)&Xh[nw * 16 + l15][kc + lk * 8];
        f16x8 xl = *(const f16x8*)&Xl[nw * 16 + l15][kc + lk * 8];
        f16x8 wh = *(const f16x8*)&Wh[fw * 16 + l15][kc + lk * 8];
        f16x8 wl = *(const f16x8*)&Wl[fw * 16 + l15][kc + lk * 8];
        acc = __builtin_amdgcn_mfma_f32_16x16x32_f16(wh, xh, acc, 0, 0, 0);
        acc = __builtin_amdgcn_mfma_f32_16x16x32_f16(wh, xl, acc, 0, 0, 0);
        acc = __builtin_amdgcn_mfma_f32_16x16x32_f16(wl, xh, acc, 0, 0, 0);
    }
    const int node = nb + nw * 16 + l15;
    const float dv = dinv[node];
    union { f16 h[4]; float2 v; } o;
#pragma unroll
    for (int r = 0; r < 4; ++r) o.h[r] = (f16)(acc[r] * dv);
    *(float2*)((char*)g2 + (size_t)node * 128 + fw * 32 + lk * 8) = o.v;
}

// ------- fused agg2 + gemm3: h3 = relu(dinv*(sum g2)+b2); g3 = dinv*(h3@W3)
// 256 threads, 32 nodes/block. Phase A: TPN=32 gather into LDS f32. Phase B:
// thread (node, f) does a 64-MAC dot via float4 LDS reads (W3 transposed).

__global__ __launch_bounds__(256) void k_ag3(const __half2* __restrict__ g,
                                             const int* __restrict__ row,
                                             const int* __restrict__ col,
                                             const float* __restrict__ dinv,
                                             const float* __restrict__ bias,
                                             const float* __restrict__ W3,
                                             float* __restrict__ g3) {
    __shared__ float h3s[32][68];
    __shared__ float W3t[8][68];
    const int t = threadIdx.x;
    const int nb = blockIdx.x * 32;

    for (int i = t; i < 512; i += 256) {
        int k = i & 63, f = i >> 6;
        W3t[f][k] = W3[k * 8 + f];
    }

    const int wv = t >> 6;
    const int l = t & 63;
    const int half = l >> 5;
    const int ln = l & 31;
    for (int i = 0; i < 4; ++i) {
        const int nloc = wv * 8 + half * 4 + i;
        const int node = nb + nloc;
        float ax = 0.f, ay = 0.f;
        const int s = row[node];
        const int e = row[node + 1];
        int idx = s;
        for (; idx + 8 <= e; idx += 8) {
            int j[8];
#pragma unroll
            for (int u = 0; u < 8; ++u) j[u] = col[idx + u];
            __half2 h[8];
#pragma unroll
            for (int u = 0; u < 8; ++u) h[u] = g[(size_t)j[u] * 32 + ln];
#pragma unroll
            for (int u = 0; u < 8; ++u) {
                float2 f2 = __half22float2(h[u]);
                ax += f2.x;
                ay += f2.y;
            }
        }
        for (; idx + 2 <= e; idx += 2) {
            int j0 = col[idx], j1 = col[idx + 1];
            float2 f0 = __half22float2(g[(size_t)j0 * 32 + ln]);
            float2 f1 = __half22float2(g[(size_t)j1 * 32 + ln]);
            ax += f0.x + f1.x;
            ay += f0.y + f1.y;
        }
        if (idx < e) {
            float2 f2 = __half22float2(g[(size_t)col[idx] * 32 + ln]);
            ax += f2.x;
            ay += f2.y;
        }
        float2 fs = __half22float2(g[(size_t)node * 32 + ln]);  // self-loop
        const float di = dinv[node];
        float2 b = *(const float2*)(bias + ln * 2);
        *(float2*)&h3s[nloc][ln * 2] =
            make_float2(fmaxf(di * (ax + fs.x) + b.x, 0.f),
                        fmaxf(di * (ay + fs.y) + b.y, 0.f));
    }
    __syncthreads();

    const int node = t >> 3;   // 0..31
    const int f = t & 7;
    float acc = 0.f;
#pragma unroll
    for (int k4 = 0; k4 < 16; ++k4) {
        float4 x = *(const float4*)&h3s[node][k4 * 4];
        float4 w = *(const float4*)&W3t[f][k4 * 4];
        acc += x.x * w.x + x.y * w.y + x.z * w.z + x.w * w.w;
    }
    g3[(size_t)(nb + node) * 8 + f] = dinv[nb + node] * acc;
}

// ------- fused agg3 + final: h4 = relu(dinv*(sum g3)+b3); out = h4@Wc + bc ---

__global__ __launch_bounds__(256) void k_agf(const float* __restrict__ g,
                                             const int* __restrict__ row,
                                             const int* __restrict__ col,
                                             const float* __restrict__ dinv,
                                             const float* __restrict__ bias,
                                             const float* __restrict__ Wc,
                                             const float* __restrict__ bc,
                                             float* __restrict__ out) {
    __shared__ float h4s[32][9];
    __shared__ float Wcs[24];
    __shared__ float bcs[3];
    const int t = threadIdx.x;
    const int nb = blockIdx.x * 32;
    if (t < 24) Wcs[t] = Wc[t];
    if (t < 3) bcs[t] = bc[t];

    const int node = t >> 3;   // 0..31
    const int lane = t & 7;
    float acc = 0.f;
    const int s = row[nb + node];
    const int e = row[nb + node + 1];
    int idx = s;
    for (; idx + 8 <= e; idx += 8) {
        int j[8];
#pragma unroll
        for (int u = 0; u < 8; ++u) j[u] = col[idx + u];
        float v[8];
#pragma unroll
        for (int u = 0; u < 8; ++u) v[u] = g[(size_t)j[u] * 8 + lane];
#pragma unroll
        for (int u = 0; u < 8; ++u) acc += v[u];
    }
    for (; idx < e; ++idx) acc += g[(size_t)col[idx] * 8 + lane];
    acc += g[(size_t)(nb + node) * 8 + lane];  // self-loop
    h4s[node][lane] = fmaxf(dinv[nb + node] * acc + bias[lane], 0.f);
    __syncthreads();

    if (t < 128 && (t & 3) < 3) {
        const int n2 = t >> 2;   // 0..31
        const int c = t & 3;     // 0..2
        float o = bcs[c];
#pragma unroll
        for (int k = 0; k < 8; ++k) o += h4s[n2][k] * Wcs[k * 3 + c];
        out[(size_t)(nb + n2) * 3 + c] = o;
    }
}

// ---------------- launch -----------------------------------------------------

extern "C" void kernel_launch(void* const* d_in, const int* in_sizes, int n_in,
                              void* d_out, int out_size, void* d_ws, size_t ws_size,
                              hipStream_t stream) {
    const float* latent = (const float*)d_in[0];
    const float* hist = (const float*)d_in[1];
    const float* subg = (const float*)d_in[2];
    const int* eidx = (const int*)d_in[3];
    const float* W1 = (const float*)d_in[4];
    const float* b1 = (const float*)d_in[5];
    const float* W2 = (const float*)d_in[6];
    const float* b2 = (const float*)d_in[7];
    const float* W3 = (const float*)d_in[8];
    const float* b3 = (const float*)d_in[9];
    const float* Wc = (const float*)d_in[10];
    const float* bc = (const float*)d_in[11];
    float* outp = (float*)d_out;

    char* ws = (char*)d_ws;
    size_t off = 0;
    auto take = [&](size_t bytes) -> void* {
        void* p = ws + off;
        off += (bytes + 255) & ~(size_t)255;
        return p;
    };
    float* dinv = (float*)take((size_t)N_NODES * 4);
    int* row = (int*)take((size_t)(N_NODES + 1) * 4);
    int* col = (int*)take((size_t)N_EDGES * 4);
    u32* entries = (u32*)take((size_t)N_EDGES * 4);
    int* bcnt = (int*)take((size_t)NBUCK * 4);
    int* boff = (int*)take((size_t)(NBUCK + 1) * 4);
    int* bcur = (int*)take((size_t)NBUCK * 4);
    __half2* bufH = (__half2*)take((size_t)N_NODES * 128 * 2);  // g1 fp16 [N][64 h2]
    __half2* bufG2 = (__half2*)take((size_t)N_NODES * 64 * 2);  // g2 fp16 [N][32 h2]
    float* bufG3 = (float*)take((size_t)N_NODES * 8 * 4);       // g3 f32 [N][8]
    f16* Wth = (f16*)take((size_t)128 * 256 * 2);               // W1^T hi (k-major)
    f16* Wtl = (f16*)take((size_t)128 * 256 * 2);               // W1^T lo
    f16* W2h = (f16*)take((size_t)64 * 128 * 2);                // W2^T hi (k-major)
    f16* W2l = (f16*)take((size_t)64 * 128 * 2);                // W2^T lo

    const int* srcp = eidx;            // edge_index[0]
    const int* dstp = eidx + N_EDGES;  // edge_index[1]

    const int scat_blocks = (N_EDGES + 8191) / 8192;  // 391

    hipMemsetAsync(bcnt, 0, (size_t)NBUCK * 4, stream);
    k_prepw<<<128, 256, 0, stream>>>(W1, Wth, Wtl);
    k_prepw2<<<32, 256, 0, stream>>>(W2, W2h, W2l);
    k_bhist<<<scat_blocks, 256, 0, stream>>>(dstp, bcnt);
    k_bscan<<<1, 256, 0, stream>>>(bcnt, boff, bcur, row);
    k_scatter<<<scat_blocks, 256, 0, stream>>>(srcp, dstp, bcur, entries);
    k_prep<<<NBUCK, 256, 0, stream>>>(entries, boff, row, dinv, col);

    k_gemm1<<<(N_NODES + 255) / 256, 1024, 0, stream>>>(latent, hist, subg, W1, Wth, Wtl, dinv, bufH);
    k_ag2<<<N_NODES / 64, 1024, 0, stream>>>(bufH, row, col, dinv, b1, W2h, W2l, bufG2);
    k_ag3<<<N_NODES / 32, 256, 0, stream>>>(bufG2, row, col, dinv, b2, W3, bufG3);
    k_agf<<<N_NODES / 32, 256, 0, stream>>>(bufG3, row, col, dinv, b3, Wc, bc, outp);
}

// Round 4
// 727.395 us; speedup vs baseline: 1.2254x; 1.0136x over previous
//
#include <hip/hip_runtime.h>
#include <hip/hip_fp16.h>

// 3-layer GCN (fp32 compute): bucketed CSR build + gemm1 + fused
// (aggregate -> GEMM) pairs.
// Round 10: gather loops slimmed in k_ag2/k_ag3/k_agf. r9 showed k_ag2 at
// VALUBusy 40% / HBM 37% -- instruction-fat gather stealing issue slots.
// Now: 8 B loads (lane owns 4 feats via f16x4 / float2), packed f32x4/f32x2
// accumulation (v_pk_add_f32), u32 saddr+voffset addressing, hoisted bias.
// Accumulation order per feature unchanged -> bit-identical results.

#define N_NODES 200000
#define N_EDGES 3200000
#define NBUCK 782            // ceil(200000/256)

static_assert(N_NODES % 64 == 0, "tiling");
static_assert((NBUCK - 1) * 256 < N_NODES && NBUCK * 256 >= N_NODES, "buckets");

typedef unsigned int u32;
typedef _Float16 f16;
typedef __attribute__((ext_vector_type(8))) _Float16 f16x8;
typedef __attribute__((ext_vector_type(4))) _Float16 f16x4;
typedef __attribute__((ext_vector_type(4))) float f32x4;
typedef __attribute__((ext_vector_type(2))) float f32x2;

// ---------------- bucket histogram ----------------

__global__ __launch_bounds__(256) void k_bhist(const int* __restrict__ dst,
                                               int* __restrict__ bcnt) {
    __shared__ int lh[NBUCK];
    int t = threadIdx.x;
    for (int b = t; b < NBUCK; b += 256) lh[b] = 0;
    __syncthreads();
    long e0 = (long)blockIdx.x * 8192;
    for (int k = 0; k < 32; ++k) {
        long e = e0 + k * 256 + t;
        if (e < N_EDGES) atomicAdd(&lh[dst[e] >> 8], 1);
    }
    __syncthreads();
    for (int b = t; b < NBUCK; b += 256)
        if (lh[b]) atomicAdd(&bcnt[b], lh[b]);
}

// ---------------- bucket scan (1 block) ----------------

__global__ __launch_bounds__(256) void k_bscan(const int* __restrict__ bcnt,
                                               int* __restrict__ boff,
                                               int* __restrict__ bcur,
                                               int* __restrict__ row) {
    __shared__ int sm[256];
    int t = threadIdx.x;
    int base = t * 4;
    int a0 = (base + 0 < NBUCK) ? bcnt[base + 0] : 0;
    int a1 = (base + 1 < NBUCK) ? bcnt[base + 1] : 0;
    int a2 = (base + 2 < NBUCK) ? bcnt[base + 2] : 0;
    int a3 = (base + 3 < NBUCK) ? bcnt[base + 3] : 0;
    int s = a0 + a1 + a2 + a3;
    sm[t] = s;
    __syncthreads();
    for (int o = 1; o < 256; o <<= 1) {
        int v = (t >= o) ? sm[t - o] : 0;
        __syncthreads();
        sm[t] += v;
        __syncthreads();
    }
    int excl = sm[t] - s;
    if (base + 0 < NBUCK) { boff[base + 0] = excl;               bcur[base + 0] = excl; }
    if (base + 1 < NBUCK) { boff[base + 1] = excl + a0;          bcur[base + 1] = excl + a0; }
    if (base + 2 < NBUCK) { boff[base + 2] = excl + a0 + a1;     bcur[base + 2] = excl + a0 + a1; }
    if (base + 3 < NBUCK) { boff[base + 3] = excl + a0 + a1 + a2; bcur[base + 3] = excl + a0 + a1 + a2; }
    if (t == 255) { boff[NBUCK] = N_EDGES; row[N_NODES] = N_EDGES; }
}

// ------------- chunked scatter: entries[p] = (src<<8)|dst_local -------------

__global__ __launch_bounds__(256) void k_scatter(const int* __restrict__ src,
                                                 const int* __restrict__ dst,
                                                 int* __restrict__ bcur,
                                                 u32* __restrict__ entries) {
    __shared__ int lh[NBUCK];
    __shared__ int base[NBUCK];
    __shared__ int lcur[NBUCK];
    int t = threadIdx.x;
    for (int b = t; b < NBUCK; b += 256) lh[b] = 0;
    __syncthreads();
    long e0 = (long)blockIdx.x * 8192;
    for (int k = 0; k < 32; ++k) {
        long e = e0 + k * 256 + t;
        if (e < N_EDGES) atomicAdd(&lh[dst[e] >> 8], 1);
    }
    __syncthreads();
    for (int b = t; b < NBUCK; b += 256) {
        base[b] = atomicAdd(&bcur[b], lh[b]);
        lcur[b] = 0;
    }
    __syncthreads();
    for (int k = 0; k < 32; ++k) {
        long e = e0 + k * 256 + t;
        if (e < N_EDGES) {
            int d = dst[e];
            int bkt = d >> 8;
            int p = base[bkt] + atomicAdd(&lcur[bkt], 1);
            entries[p] = ((u32)src[e] << 8) | (u32)(d & 255);
        }
    }
}

// --- per-bucket prep: deg/row/dinv + col fill, all L2-local to one block ----

__global__ __launch_bounds__(256) void k_prep(const u32* __restrict__ entries,
                                              const int* __restrict__ boff,
                                              int* __restrict__ row,
                                              float* __restrict__ dinv,
                                              int* __restrict__ col) {
    __shared__ int lh[256];
    __shared__ int sc[256];
    __shared__ int cur[256];
    const int b = blockIdx.x, t = threadIdx.x;
    const int s = boff[b], e = boff[b + 1];
    const int cnt = e - s;
    lh[t] = 0;
    __syncthreads();
    for (int i = t; i < cnt; i += 256) atomicAdd(&lh[entries[s + i] & 255], 1);
    __syncthreads();
    int my = lh[t];
    sc[t] = my;
    __syncthreads();
    for (int o = 1; o < 256; o <<= 1) {
        int v = (t >= o) ? sc[t - o] : 0;
        __syncthreads();
        sc[t] += v;
        __syncthreads();
    }
    int excl = sc[t] - my;
    int node = b * 256 + t;
    if (node < N_NODES) {
        row[node] = s + excl;
        dinv[node] = rsqrtf((float)(my + 1));  // +1 self-loop
    }
    cur[t] = s + excl;
    __syncthreads();
    for (int i = t; i < cnt; i += 256) {
        u32 en = entries[s + i];
        int p = atomicAdd(&cur[en & 255], 1);
        col[p] = (int)(en >> 8);
    }
}

// ------- W1 pre-split/transpose: Wth/Wtl[f][k] f16 hi/lo, k-major -----------

__global__ __launch_bounds__(256) void k_prepw(const float* __restrict__ W,
                                               f16* __restrict__ Wth,
                                               f16* __restrict__ Wtl) {
    int t = blockIdx.x * 256 + threadIdx.x;  // 0..32767
    int k = t >> 7;                          // 0..255 (tail rows 256/257 stay fp32)
    int f = t & 127;
    float w = W[k * 128 + f];
    f16 hi = (f16)w;
    f16 lo = (f16)(w - (float)hi);
    Wth[f * 256 + k] = hi;
    Wtl[f * 256 + k] = lo;
}

// ------- W2 pre-split/transpose: [128][64] -> hi/lo f16 [64][128] k-major ----

__global__ __launch_bounds__(256) void k_prepw2(const float* __restrict__ W2,
                                                f16* __restrict__ Wh,
                                                f16* __restrict__ Wl) {
    int t = blockIdx.x * 256 + threadIdx.x;  // 0..8191
    int k = t >> 6;                          // 0..127
    int f = t & 63;
    float w = W2[k * 64 + f];
    f16 hi = (f16)w;
    Wh[f * 128 + k] = hi;
    Wl[f * 128 + k] = (f16)(w - (float)hi);
}

// ------- GEMM layer 1 (MFMA): [N,258]x[258,128], epilogue g = dinv*h -> fp16
// 1024 threads = 16 waves, 256 nodes/block, 16 nodes/wave. W hi+lo in LDS
// (128 KB, XOR-swizzled), staged once; X fragments global->reg (8 consecutive
// floats/lane); no per-K-step barriers. 3-term split-f16 = ~fp32 precision.

__global__ __launch_bounds__(1024) void k_gemm1(const float* __restrict__ X,
                                                const float* __restrict__ hist,
                                                const float* __restrict__ subg,
                                                const float* __restrict__ W,
                                                const f16* __restrict__ Wth,
                                                const f16* __restrict__ Wtl,
                                                const float* __restrict__ dinv,
                                                __half2* __restrict__ g1) {
    __shared__ f16 Ws[2][128 * 256];   // [hi/lo][row*256+k], byte^((row&7)<<4)
    const int t = threadIdx.x;

    // ---- stage W once (swizzled writes, coalesced global reads) ----
    {
        const int r = t >> 3;          // feat row 0..127
        const int seg = t & 7;         // 32 halves each
        const f16* gh = Wth + r * 256 + seg * 32;
        const f16* gl = Wtl + r * 256 + seg * 32;
        const int sw = (r & 7) << 4;
        const int base = r * 512 + seg * 64;   // byte offset, 16B-granular
        char* wsh = (char*)&Ws[0][0];
        char* wsl = (char*)&Ws[1][0];
#pragma unroll
        for (int q = 0; q < 4; ++q) {
            *(f16x8*)(wsh + ((base + q * 16) ^ sw)) = *(const f16x8*)(gh + q * 8);
            *(f16x8*)(wsl + ((base + q * 16) ^ sw)) = *(const f16x8*)(gl + q * 8);
        }
    }

    const int wv = t >> 6;          // wave 0..15
    const int l = t & 63;
    const int l15 = l & 15;         // node within wave / D column
    const int lk = l >> 4;          // k-chunk 0..3 (8 halves each)
    const int nb = blockIdx.x * 256;
    const int node = nb + wv * 16 + l15;
    const int xrow = node < N_NODES ? node : N_NODES - 1;  // clamp (stores guarded)
    const float* xbase = X + (size_t)xrow * 256 + lk * 8;

    f32x4 acc[8];
#pragma unroll
    for (int fb = 0; fb < 8; ++fb) acc[fb] = (f32x4){0.f, 0.f, 0.f, 0.f};

    // prefetch K-tile 0 (in flight across the staging barrier)
    float4 pa = *(const float4*)(xbase + 0);
    float4 pb = *(const float4*)(xbase + 4);

    __syncthreads();  // W staged -- the only barrier

    const char* wsh = (const char*)&Ws[0][0];
    const char* wsl = (const char*)&Ws[1][0];
    const int sw = (l15 & 7) << 4;  // row&7 == l15&7 for every fb

    for (int kc = 0; kc < 256; kc += 32) {
        float xs[8] = {pa.x, pa.y, pa.z, pa.w, pb.x, pb.y, pb.z, pb.w};
        if (kc + 32 < 256) {  // issue next-tile loads before compute
            pa = *(const float4*)(xbase + kc + 32);
            pb = *(const float4*)(xbase + kc + 36);
        }
        union { f16 h[8]; f16x8 v; } H, L;
#pragma unroll
        for (int i = 0; i < 8; ++i) {
            f16 h = (f16)xs[i];
            H.h[i] = h;
            L.h[i] = (f16)(xs[i] - (float)h);
        }
        f16x8 xh = H.v, xl = L.v;

        const int koff = ((kc + lk * 8) * 2) ^ sw;  // swizzled within-row byte off
#pragma unroll
        for (int fb = 0; fb < 8; ++fb) {
            const int off = (fb * 16 + l15) * 512 + koff;
            f16x8 wh = *(const f16x8*)(wsh + off);
            f16x8 wl = *(const f16x8*)(wsl + off);
            acc[fb] = __builtin_amdgcn_mfma_f32_16x16x32_f16(wh, xh, acc[fb], 0, 0, 0);
            acc[fb] = __builtin_amdgcn_mfma_f32_16x16x32_f16(wh, xl, acc[fb], 0, 0, 0);
            acc[fb] = __builtin_amdgcn_mfma_f32_16x16x32_f16(wl, xh, acc[fb], 0, 0, 0);
        }
    }

    // epilogue: K tail rows 256 (hist), 257 (subg) in exact fp32; scale dinv.
    const bool ok = node < N_NODES;
    const float hh = hist[xrow];
    const float ss = subg[xrow];
    const float dv = dinv[xrow];
    char* orow = (char*)g1 + (size_t)node * 256;
#pragma unroll
    for (int fb = 0; fb < 8; ++fb) {
        const int f0 = fb * 16 + lk * 4;  // 4 consecutive feats per lane
        float4 w6 = *(const float4*)(W + 256 * 128 + f0);
        float4 w7 = *(const float4*)(W + 257 * 128 + f0);
        union { f16 h[4]; float2 v; } o;
        o.h[0] = (f16)((acc[fb][0] + hh * w6.x + ss * w7.x) * dv);
        o.h[1] = (f16)((acc[fb][1] + hh * w6.y + ss * w7.y) * dv);
        o.h[2] = (f16)((acc[fb][2] + hh * w6.z + ss * w7.z) * dv);
        o.h[3] = (f16)((acc[fb][3] + hh * w6.w + ss * w7.w) * dv);
        if (ok) *(float2*)(orow + fb * 32 + lk * 8) = o.v;
    }
}

// ------- fused agg1 + gemm2: h2 = relu(dinv*(sum g1)+b1); g2 = dinv*(h2@W2)
// 1024 threads, 64 nodes/block. Phase A: lane owns 4 feats (f16x4, 8 B loads),
// wave handles 2 nodes concurrently x 2 iters; f32x4 pk accumulation; u32
// saddr+voffset addressing. Phase B: 16 waves, one 16x16 MFMA tile each.

__global__ __launch_bounds__(1024) void k_ag2(const __half2* __restrict__ g,
                                              const int* __restrict__ row,
                                              const int* __restrict__ col,
                                              const float* __restrict__ dinv,
                                              const float* __restrict__ bias,
                                              const f16* __restrict__ W2hg,
                                              const f16* __restrict__ W2lg,
                                              __half2* __restrict__ g2) {
    __shared__ f16 Xh[64][136];
    __shared__ f16 Xl[64][136];
    __shared__ f16 Wh[64][136];
    __shared__ f16 Wl[64][136];
    const int t = threadIdx.x;
    const int nb = blockIdx.x * 64;

    // stage W2 hi/lo (once)
    {
        const int r = t >> 4;          // 0..63
        const int sg = (t & 15) * 8;   // 8 halves
        *(f16x8*)&Wh[r][sg] = *(const f16x8*)(W2hg + r * 128 + sg);
        *(f16x8*)&Wl[r][sg] = *(const f16x8*)(W2lg + r * 128 + sg);
    }

    // ---- phase A: aggregate. lane owns feats 4*ln..+3; hf = node-of-pair ----
    const int wv = t >> 6;
    const int l = t & 63;
    const int hf = l >> 5;         // 0/1
    const int ln = l & 31;         // f16x4 index within row (32 per row)
    const f16x4* gp = (const f16x4*)g;   // row stride 32 f16x4
    const float4 b4 = *(const float4*)(bias + ln * 4);
    for (int i = 0; i < 2; ++i) {
        const int nloc = wv * 4 + hf * 2 + i;
        const int node = nb + nloc;
        f32x4 a = (f32x4){0.f, 0.f, 0.f, 0.f};
        const int s = row[node];
        const int e = row[node + 1];
        int idx = s;
        for (; idx + 8 <= e; idx += 8) {
            u32 off[8];
            f16x4 h[8];
#pragma unroll
            for (int u = 0; u < 8; ++u) off[u] = ((u32)col[idx + u] << 5) + ln;
#pragma unroll
            for (int u = 0; u < 8; ++u) h[u] = gp[off[u]];
#pragma unroll
            for (int u = 0; u < 8; ++u) a += __builtin_convertvector(h[u], f32x4);
        }
        for (; idx < e; ++idx)
            a += __builtin_convertvector(gp[((u32)col[idx] << 5) + ln], f32x4);
        f32x4 fs = __builtin_convertvector(gp[((u32)node << 5) + ln], f32x4);
        const float di = dinv[node];
        float v0 = fmaxf(di * (a[0] + fs[0]) + b4.x, 0.f);
        float v1 = fmaxf(di * (a[1] + fs[1]) + b4.y, 0.f);
        float v2 = fmaxf(di * (a[2] + fs[2]) + b4.z, 0.f);
        float v3 = fmaxf(di * (a[3] + fs[3]) + b4.w, 0.f);
        f16 h0 = (f16)v0, h1 = (f16)v1, h2 = (f16)v2, h3 = (f16)v3;
        f16x4 hi = {h0, h1, h2, h3};
        f16x4 lo = {(f16)(v0 - (float)h0), (f16)(v1 - (float)h1),
                    (f16)(v2 - (float)h2), (f16)(v3 - (float)h3)};
        *(f16x4*)&Xh[nloc][ln * 4] = hi;
        *(f16x4*)&Xl[nloc][ln * 4] = lo;
    }
    __syncthreads();

    // ---- phase B: 16 waves x one 16x16 MFMA tile, K=128 ----
    const int l15 = l & 15;
    const int lk = l >> 4;
    const int nw = wv & 3;    // node tile
    const int fw = wv >> 2;   // feat tile
    f32x4 acc = (f32x4){0.f, 0.f, 0.f, 0.f};
#pragma unroll
    for (int kc = 0; kc < 128; kc += 32) {
        f16x8 xh = *(const f16x8*)&Xh[nw * 16 + l15][kc + lk * 8];
        f16x8 xl = *(const f16x8*)&Xl[nw * 16 + l15][kc + lk * 8];
        f16x8 wh = *(const f16x8*)&Wh[fw * 16 + l15][kc + lk * 8];
        f16x8 wl = *(const f16x8*)&Wl[fw * 16 + l15][kc + lk * 8];
        acc = __builtin_amdgcn_mfma_f32_16x16x32_f16(wh, xh, acc, 0, 0, 0);
        acc = __builtin_amdgcn_mfma_f32_16x16x32_f16(wh, xl, acc, 0, 0, 0);
        acc = __builtin_amdgcn_mfma_f32_16x16x32_f16(wl, xh, acc, 0, 0, 0);
    }
    const int node = nb + nw * 16 + l15;
    const float dv = dinv[node];
    union { f16 h[4]; float2 v; } o;
#pragma unroll
    for (int r = 0; r < 4; ++r) o.h[r] = (f16)(acc[r] * dv);
    *(float2*)((char*)g2 + (size_t)node * 128 + fw * 32 + lk * 8) = o.v;
}

// ------- fused agg2 + gemm3: h3 = relu(dinv*(sum g2)+b2); g3 = dinv*(h3@W3)
// 256 threads, 32 nodes/block. Phase A: lane owns 4 feats (f16x4), wave does
// 4 nodes concurrently x 2 iters. Phase B: thread (node,f) 64-MAC dot.

__global__ __launch_bounds__(256) void k_ag3(const __half2* __restrict__ g,
                                             const int* __restrict__ row,
                                             const int* __restrict__ col,
                                             const float* __restrict__ dinv,
                                             const float* __restrict__ bias,
                                             const float* __restrict__ W3,
                                             float* __restrict__ g3) {
    __shared__ float h3s[32][68];
    __shared__ float W3t[8][68];
    const int t = threadIdx.x;
    const int nb = blockIdx.x * 32;

    for (int i = t; i < 512; i += 256) {
        int k = i & 63, f = i >> 6;
        W3t[f][k] = W3[k * 8 + f];
    }

    const int wv = t >> 6;        // 0..3
    const int l = t & 63;
    const int q = l >> 4;         // 0..3: node-of-quad
    const int ln = l & 15;        // f16x4 index (16 per 64-f16 row)
    const f16x4* gp = (const f16x4*)g;   // row stride 16 f16x4
    const float4 b4 = *(const float4*)(bias + ln * 4);
    for (int i = 0; i < 2; ++i) {
        const int nloc = wv * 8 + q * 2 + i;
        const int node = nb + nloc;
        f32x4 a = (f32x4){0.f, 0.f, 0.f, 0.f};
        const int s = row[node];
        const int e = row[node + 1];
        int idx = s;
        for (; idx + 8 <= e; idx += 8) {
            u32 off[8];
            f16x4 h[8];
#pragma unroll
            for (int u = 0; u < 8; ++u) off[u] = ((u32)col[idx + u] << 4) + ln;
#pragma unroll
            for (int u = 0; u < 8; ++u) h[u] = gp[off[u]];
#pragma unroll
            for (int u = 0; u < 8; ++u) a += __builtin_convertvector(h[u], f32x4);
        }
        for (; idx < e; ++idx)
            a += __builtin_convertvector(gp[((u32)col[idx] << 4) + ln], f32x4);
        f32x4 fs = __builtin_convertvector(gp[((u32)node << 4) + ln], f32x4);
        const float di = dinv[node];
        float4 o;
        o.x = fmaxf(di * (a[0] + fs[0]) + b4.x, 0.f);
        o.y = fmaxf(di * (a[1] + fs[1]) + b4.y, 0.f);
        o.z = fmaxf(di * (a[2] + fs[2]) + b4.z, 0.f);
        o.w = fmaxf(di * (a[3] + fs[3]) + b4.w, 0.f);
        *(float4*)&h3s[nloc][ln * 4] = o;
    }
    __syncthreads();

    const int node = t >> 3;   // 0..31
    const int f = t & 7;
    float acc = 0.f;
#pragma unroll
    for (int k4 = 0; k4 < 16; ++k4) {
        float4 x = *(const float4*)&h3s[node][k4 * 4];
        float4 w = *(const float4*)&W3t[f][k4 * 4];
        acc += x.x * w.x + x.y * w.y + x.z * w.z + x.w * w.w;
    }
    g3[(size_t)(nb + node) * 8 + f] = dinv[nb + node] * acc;
}

// ------- fused agg3 + final: h4 = relu(dinv*(sum g3)+b3); out = h4@Wc + bc ---
// 64 nodes/block; lane c=t&3 owns float2 feats 2c..2c+1 (8 B loads, pk adds).

__global__ __launch_bounds__(256) void k_agf(const float* __restrict__ g,
                                             const int* __restrict__ row,
                                             const int* __restrict__ col,
                                             const float* __restrict__ dinv,
                                             const float* __restrict__ bias,
                                             const float* __restrict__ Wc,
                                             const float* __restrict__ bc,
                                             float* __restrict__ out) {
    __shared__ float h4s[64][10];
    __shared__ float Wcs[24];
    __shared__ float bcs[3];
    const int t = threadIdx.x;
    const int nb = blockIdx.x * 64;
    if (t < 24) Wcs[t] = Wc[t];
    if (t < 3) bcs[t] = bc[t];

    const int node = t >> 2;   // 0..63
    const int c = t & 3;       // float2 index within 8-f32 row
    const f32x2* gp = (const f32x2*)g;   // row stride 4 f32x2
    const float2 b2 = *(const float2*)(bias + c * 2);
    f32x2 a = (f32x2){0.f, 0.f};
    const int s = row[nb + node];
    const int e = row[nb + node + 1];
    int idx = s;
    for (; idx + 8 <= e; idx += 8) {
        u32 off[8];
        f32x2 v[8];
#pragma unroll
        for (int u = 0; u < 8; ++u) off[u] = ((u32)col[idx + u] << 2) + c;
#pragma unroll
        for (int u = 0; u < 8; ++u) v[u] = gp[off[u]];
#pragma unroll
        for (int u = 0; u < 8; ++u) a += v[u];
    }
    for (; idx < e; ++idx) a += gp[((u32)col[idx] << 2) + c];
    a += gp[((u32)(nb + node) << 2) + c];  // self-loop
    const float di = dinv[nb + node];
    float2 o;
    o.x = fmaxf(di * a[0] + b2.x, 0.f);
    o.y = fmaxf(di * a[1] + b2.y, 0.f);
    *(float2*)&h4s[node][c * 2] = o;
    __syncthreads();

    if ((t & 3) < 3) {
        const int n2 = t >> 2;   // 0..63
        const int cc = t & 3;    // 0..2
        float o2 = bcs[cc];
#pragma unroll
        for (int k = 0; k < 8; ++k) o2 += h4s[n2][k] * Wcs[k * 3 + cc];
        out[(size_t)(nb + n2) * 3 + cc] = o2;
    }
}

// ---------------- launch -----------------------------------------------------

extern "C" void kernel_launch(void* const* d_in, const int* in_sizes, int n_in,
                              void* d_out, int out_size, void* d_ws, size_t ws_size,
                              hipStream_t stream) {
    const float* latent = (const float*)d_in[0];
    const float* hist = (const float*)d_in[1];
    const float* subg = (const float*)d_in[2];
    const int* eidx = (const int*)d_in[3];
    const float* W1 = (const float*)d_in[4];
    const float* b1 = (const float*)d_in[5];
    const float* W2 = (const float*)d_in[6];
    const float* b2 = (const float*)d_in[7];
    const float* W3 = (const float*)d_in[8];
    const float* b3 = (const float*)d_in[9];
    const float* Wc = (const float*)d_in[10];
    const float* bc = (const float*)d_in[11];
    float* outp = (float*)d_out;

    char* ws = (char*)d_ws;
    size_t off = 0;
    auto take = [&](size_t bytes) -> void* {
        void* p = ws + off;
        off += (bytes + 255) & ~(size_t)255;
        return p;
    };
    float* dinv = (float*)take((size_t)N_NODES * 4);
    int* row = (int*)take((size_t)(N_NODES + 1) * 4);
    int* col = (int*)take((size_t)N_EDGES * 4);
    u32* entries = (u32*)take((size_t)N_EDGES * 4);
    int* bcnt = (int*)take((size_t)NBUCK * 4);
    int* boff = (int*)take((size_t)(NBUCK + 1) * 4);
    int* bcur = (int*)take((size_t)NBUCK * 4);
    __half2* bufH = (__half2*)take((size_t)N_NODES * 128 * 2);  // g1 fp16 [N][64 h2]
    __half2* bufG2 = (__half2*)take((size_t)N_NODES * 64 * 2);  // g2 fp16 [N][32 h2]
    float* bufG3 = (float*)take((size_t)N_NODES * 8 * 4);       // g3 f32 [N][8]
    f16* Wth = (f16*)take((size_t)128 * 256 * 2);               // W1^T hi (k-major)
    f16* Wtl = (f16*)take((size_t)128 * 256 * 2);               // W1^T lo
    f16* W2h = (f16*)take((size_t)64 * 128 * 2);                // W2^T hi (k-major)
    f16* W2l = (f16*)take((size_t)64 * 128 * 2);                // W2^T lo

    const int* srcp = eidx;            // edge_index[0]
    const int* dstp = eidx + N_EDGES;  // edge_index[1]

    const int scat_blocks = (N_EDGES + 8191) / 8192;  // 391

    hipMemsetAsync(bcnt, 0, (size_t)NBUCK * 4, stream);
    k_prepw<<<128, 256, 0, stream>>>(W1, Wth, Wtl);
    k_prepw2<<<32, 256, 0, stream>>>(W2, W2h, W2l);
    k_bhist<<<scat_blocks, 256, 0, stream>>>(dstp, bcnt);
    k_bscan<<<1, 256, 0, stream>>>(bcnt, boff, bcur, row);
    k_scatter<<<scat_blocks, 256, 0, stream>>>(srcp, dstp, bcur, entries);
    k_prep<<<NBUCK, 256, 0, stream>>>(entries, boff, row, dinv, col);

    k_gemm1<<<(N_NODES + 255) / 256, 1024, 0, stream>>>(latent, hist, subg, W1, Wth, Wtl, dinv, bufH);
    k_ag2<<<N_NODES / 64, 1024, 0, stream>>>(bufH, row, col, dinv, b1, W2h, W2l, bufG2);
    k_ag3<<<N_NODES / 32, 256, 0, stream>>>(bufG2, row, col, dinv, b2, W3, bufG3);
    k_agf<<<N_NODES / 64, 256, 0, stream>>>(bufG3, row, col, dinv, b3, Wc, bc, outp);
}